// Round 21
// baseline (200.108 us; speedup 1.0000x reference)
//
#include <hip/hip_runtime.h>
#include <hip/hip_bf16.h>

typedef __attribute__((ext_vector_type(8))) short bf16x8;
typedef __attribute__((ext_vector_type(4))) float f32x4;

__device__ __forceinline__ f32x4 mfma16(bf16x8 a, bf16x8 b, f32x4 c) {
  return __builtin_amdgcn_mfma_f32_16x16x32_bf16(a, b, c, 0, 0, 0);
}

__device__ __forceinline__ void gload_lds16(const void* g, void* l) {
  __builtin_amdgcn_global_load_lds(
      (__attribute__((address_space(1))) void*)(g),
      (__attribute__((address_space(3))) void*)(l), 16, 0, 0);
}

__device__ __forceinline__ unsigned short f2bf(float f) {
  union { __hip_bfloat16 h; unsigned short u; } cv;
  cv.h = __float2bfloat16(f);
  return cv.u;
}

__device__ __forceinline__ float bf2f_(unsigned short u) {
  union { unsigned int i; float f; } c;
  c.i = (unsigned int)u << 16;
  return c.f;
}

__device__ __forceinline__ void split2(float v, unsigned short& hb, unsigned short& lb) {
  __hip_bfloat16 hh = __float2bfloat16(v);
  union { __hip_bfloat16 h; unsigned short u; } cv;
  cv.h = hh;
  hb = cv.u;
  lb = f2bf(v - __bfloat162float(hh));
}

// fast gelu: tanh(u) = (e^{2u}-1)/(e^{2u}+1) via v_exp + v_rcp
__device__ __forceinline__ float gelu_f(float v) {
  float u = 0.7978845608028654f * (v + 0.044715f * v * v * v);
  float t = __expf(2.0f * u);
  float th = (t - 1.0f) * __builtin_amdgcn_rcpf(t + 1.0f);
  return 0.5f * v * (1.0f + th);
}

// ---------------- fused transpose+cast-split for all 4 weights (one launch) ----------------
__global__ __launch_bounds__(256) void transpose_all(
    const float* __restrict__ w0, const float* __restrict__ w1,
    const float* __restrict__ w2, const float* __restrict__ w3,
    unsigned short* __restrict__ h0, unsigned short* __restrict__ l0,
    unsigned short* __restrict__ h1, unsigned short* __restrict__ l1,
    unsigned short* __restrict__ h2, unsigned short* __restrict__ l2,
    unsigned short* __restrict__ h3, unsigned short* __restrict__ l3) {
  __shared__ float tile[32][33];
  const int id = blockIdx.x;
  const float* in;
  unsigned short *oh, *ol;
  int K, N, nx, local;
  if (id < 1728)      { in = w0; oh = h0; ol = l0; K = 768;  N = 2304; nx = 72; local = id; }
  else if (id < 2304) { in = w1; oh = h1; ol = l1; K = 768;  N = 768;  nx = 24; local = id - 1728; }
  else if (id < 4608) { in = w2; oh = h2; ol = l2; K = 768;  N = 3072; nx = 96; local = id - 2304; }
  else                { in = w3; oh = h3; ol = l3; K = 3072; N = 768;  nx = 24; local = id - 4608; }
  const int n0 = (local % nx) * 32, k0 = (local / nx) * 32;
  const int tx = threadIdx.x & 31, ty = threadIdx.x >> 5;  // ty 0..7
#pragma unroll
  for (int i = 0; i < 32; i += 8)
    tile[ty + i][tx] = in[(size_t)(k0 + ty + i) * N + (n0 + tx)];
  __syncthreads();
#pragma unroll
  for (int i = 0; i < 32; i += 8) {
    unsigned short hb, lb;
    split2(tile[tx][ty + i], hb, lb);
    const size_t idx = (size_t)(n0 + ty + i) * K + (k0 + tx);
    oh[idx] = hb;
    ol[idx] = lb;
  }
}

// ---------------- LayerNorm (C=768) f32 -> bf16 (hi only) ----------------
__global__ __launch_bounds__(192) void ln_hi(
    const float* __restrict__ x, const float* __restrict__ w,
    const float* __restrict__ bb, unsigned short* __restrict__ outh) {
  const int row = blockIdx.x;
  const int t = threadIdx.x;  // 0..191, 4 floats each
  const float4 v = ((const float4*)(x + (size_t)row * 768))[t];
  float s = v.x + v.y + v.z + v.w;
  float q = v.x * v.x + v.y * v.y + v.z * v.z + v.w * v.w;
#pragma unroll
  for (int off = 1; off < 64; off <<= 1) {
    s += __shfl_xor(s, off);
    q += __shfl_xor(q, off);
  }
  __shared__ float ss[3], qq[3];
  const int wid = t >> 6;
  if ((t & 63) == 0) { ss[wid] = s; qq[wid] = q; }
  __syncthreads();
  const float S = ss[0] + ss[1] + ss[2];
  const float Q = qq[0] + qq[1] + qq[2];
  const float mu = S * (1.0f / 768.0f);
  const float var = Q * (1.0f / 768.0f) - mu * mu;
  const float rstd = rsqrtf(var + 1e-5f);
  const float4 wv = ((const float4*)w)[t];
  const float4 bv = ((const float4*)bb)[t];
  ushort4 oh;
  oh.x = f2bf((v.x - mu) * rstd * wv.x + bv.x);
  oh.y = f2bf((v.y - mu) * rstd * wv.y + bv.y);
  oh.z = f2bf((v.z - mu) * rstd * wv.z + bv.z);
  oh.w = f2bf((v.w - mu) * rstd * wv.w + bv.w);
  ((ushort4*)(outh + (size_t)row * 768))[t] = oh;
}

// ---------------- fc2 reduce: out = x1 + p0 + p1 (partials bf16, bias folded in p0) ----
__global__ __launch_bounds__(256) void fc2_reduce(
    const float* __restrict__ x1, const unsigned short* __restrict__ p0,
    const unsigned short* __restrict__ p1, float* __restrict__ out) {
  const size_t i = ((size_t)blockIdx.x * 256 + threadIdx.x) * 4;
  const float4 xv = *(const float4*)(x1 + i);
  const ushort4 a = *(const ushort4*)(p0 + i);
  const ushort4 b = *(const ushort4*)(p1 + i);
  float4 o;
  o.x = xv.x + bf2f_(a.x) + bf2f_(b.x);
  o.y = xv.y + bf2f_(a.y) + bf2f_(b.y);
  o.z = xv.z + bf2f_(a.z) + bf2f_(b.z);
  o.w = xv.w + bf2f_(a.w) + bf2f_(b.w);
  *(float4*)(out + i) = o;
}

// ============ 128x128 2-phase GEMM (augmented-K split-bf16), BK=64, 8 waves ============
// M-major grid (XCD = m-block%8). NTERM=1: qkv+fc1 (r19-validated). SPLITK=1: fc2.
// EPI: 0 bf16; 1 gelu+bf16; 2 f32 resid; 3 bf16 with 0.125*log2(e) on cols<768
// (Q pre-scale: attention scores land in log2 domain -> attn uses native exp2).
template <int EPI, int NTERM, int NKT, int SPLITK>
__global__ __launch_bounds__(512, 2) void gemmT(
    const unsigned short* __restrict__ Ah, const unsigned short* __restrict__ Al,
    const unsigned short* __restrict__ Bh, const unsigned short* __restrict__ Bl,
    const float* __restrict__ bias, const float* __restrict__ resid,
    void* __restrict__ outp, int N, int K) {
  __shared__ __align__(16) char lds[65536];
  const int tid = threadIdx.x;
  const int lane = tid & 63, wid = tid >> 6;
  const int wr = wid >> 1, wc = wid & 1;  // wave -> 32-row x 64-col output region
  const int rl = lane & 15, g = lane >> 4;
  const int m0 = blockIdx.x * 128, n0 = blockIdx.y * 128;  // M-major
  const int NT = NTERM * NKT;

  const int srw = lane >> 3;
  const int csrc = (lane & 7) ^ srw;
  const size_t a_base = (size_t)(m0 + wid * 8 + srw) * K + csrc * 8;
  const size_t b_base = (size_t)(n0 + wid * 8 + srw) * K + csrc * 8;

  auto stageA = [&](int buf, int half, int tile) {
    const int tt = (tile < NT) ? tile : 0;
    const int term = tt / NKT, kc = tt - term * NKT;
    const unsigned short* src = (NTERM == 3 && term == 2) ? Al : Ah;
    const unsigned short* gp = src + a_base + (size_t)half * 64 * K + kc * 64;
    gload_lds16(gp, lds + buf * 16384 + half * 8192 + wid * 1024);
  };
  auto stageB = [&](int buf, int half, int tile) {
    const int tt = (tile < NT) ? tile : 0;
    const int term = tt / NKT, kc = tt - term * NKT;
    const unsigned short* src = (term == 1) ? Bl : Bh;
    if (SPLITK) src = blockIdx.z ? Bl : Bh;
    const unsigned short* gp = src + b_base + (size_t)half * 64 * K + kc * 64;
    gload_lds16(gp, lds + 32768 + buf * 16384 + half * 8192 + wid * 1024);
  };
  auto rdA = [&](int buf, int mf, int s) -> bf16x8 {
    const int row = wr * 32 + mf * 16 + rl;
    const int c = (s * 4 + g) ^ (row & 7);
    return *(const bf16x8*)(lds + buf * 16384 + row * 128 + c * 16);
  };
  auto rdB = [&](int buf, int nfp, int s) -> bf16x8 {
    const int row = wc * 64 + nfp * 16 + rl;
    const int c = (s * 4 + g) ^ (row & 7);
    return *(const bf16x8*)(lds + 32768 + buf * 16384 + row * 128 + c * 16);
  };

  f32x4 acc[2][4];
#pragma unroll
  for (int i = 0; i < 2; ++i)
#pragma unroll
    for (int j = 0; j < 4; ++j) acc[i][j] = 0.0f;

  bf16x8 af[2][2], bfr[2][2];

  stageA(0, 0, 0); stageA(0, 1, 0);
  stageB(0, 0, 0); stageB(0, 1, 0);
  stageA(1, 0, 1); stageA(1, 1, 1);
  asm volatile("s_waitcnt vmcnt(2)" ::: "memory");
  __builtin_amdgcn_s_barrier();

#define TILE(P, T)                                                                \
  {                                                                               \
    _Pragma("unroll") for (int mf = 0; mf < 2; ++mf)                              \
    _Pragma("unroll") for (int s = 0; s < 2; ++s) af[mf][s] = rdA(P, mf, s);      \
    _Pragma("unroll") for (int nf = 0; nf < 2; ++nf)                              \
    _Pragma("unroll") for (int s = 0; s < 2; ++s) bfr[nf][s] = rdB(P, nf, s);     \
    stageB((P) ^ 1, 0, (T) + 1);                                                  \
    stageB((P) ^ 1, 1, (T) + 1);                                                  \
    __builtin_amdgcn_s_barrier();                                                 \
    asm volatile("s_waitcnt lgkmcnt(0)" ::: "memory");                            \
    __builtin_amdgcn_sched_barrier(0);                                            \
    __builtin_amdgcn_s_setprio(1);                                                \
    _Pragma("unroll") for (int mf = 0; mf < 2; ++mf)                              \
    _Pragma("unroll") for (int nf = 0; nf < 2; ++nf)                              \
    _Pragma("unroll") for (int s = 0; s < 2; ++s)                                 \
        acc[mf][nf] = mfma16(af[mf][s], bfr[nf][s], acc[mf][nf]);                 \
    __builtin_amdgcn_s_setprio(0);                                                \
    __builtin_amdgcn_s_barrier();                                                 \
    _Pragma("unroll") for (int nf = 0; nf < 2; ++nf)                              \
    _Pragma("unroll") for (int s = 0; s < 2; ++s) bfr[nf][s] = rdB(P, 2 + nf, s); \
    stageA(P, 0, (T) + 2);                                                        \
    stageA(P, 1, (T) + 2);                                                        \
    __builtin_amdgcn_s_barrier();                                                 \
    asm volatile("s_waitcnt lgkmcnt(0)" ::: "memory");                            \
    __builtin_amdgcn_sched_barrier(0);                                            \
    __builtin_amdgcn_s_setprio(1);                                                \
    _Pragma("unroll") for (int mf = 0; mf < 2; ++mf)                              \
    _Pragma("unroll") for (int nf = 0; nf < 2; ++nf)                              \
    _Pragma("unroll") for (int s = 0; s < 2; ++s)                                 \
        acc[mf][2 + nf] = mfma16(af[mf][s], bfr[nf][s], acc[mf][2 + nf]);         \
    __builtin_amdgcn_s_setprio(0);                                                \
    asm volatile("s_waitcnt vmcnt(2)" ::: "memory");                              \
    __builtin_amdgcn_s_barrier();                                                 \
  }

  for (int t = 0; t < NT; t += 2) {
    TILE(0, t)
    TILE(1, t + 1)
  }
#undef TILE

  __hip_bfloat16* outb16 = (__hip_bfloat16*)outp;
  if (SPLITK)
    outb16 += (size_t)blockIdx.z * (size_t)gridDim.x * 128 * (size_t)N;
  float* outf = (float*)outp;
#pragma unroll
  for (int nfp = 0; nfp < 4; ++nfp) {
    const int col = n0 + wc * 64 + nfp * 16 + rl;
    float bia = bias[col];
    if (SPLITK && blockIdx.z) bia = 0.0f;
#pragma unroll
    for (int mf = 0; mf < 2; ++mf) {
      const int rowb = m0 + wr * 32 + mf * 16 + g * 4;
#pragma unroll
      for (int r = 0; r < 4; ++r) {
        float val = acc[mf][nfp][r] + bia;
        const size_t idx = (size_t)(rowb + r) * N + col;
        if (EPI == 1) val = gelu_f(val);
        if (EPI == 3 && col < 768) val *= 0.180336880111120f;  // 0.125*log2(e)
        if (EPI == 2)
          outf[idx] = resid[idx] + val;
        else
          outb16[idx] = __float2bfloat16(val);
      }
    }
  }
}

// ---------------- fused causal attention (swapped-QK^T, KVBLK=128, XCD-local grid) ----------------
// r21: r19 structure (full P [16][128], 48KB LDS, single-phase PV) + log2-domain
// softmax (Q pre-scaled by 0.125*log2e in qkv epilogue; native exp2, no muls).
__global__ __launch_bounds__(256) void attn_kernel(
    const unsigned short* __restrict__ qkv, unsigned short* __restrict__ yh) {
  const int T = 2048, C3 = 2304, NH = 12;
  const int bh = blockIdx.x;            // 0..23 -> XCD = bh%8
  const int bq = blockIdx.y;            // 0..31
  const int qt = (bq & 1) ? (31 - (bq >> 1)) : (bq >> 1);  // long/short pairing
  const int b = bh / NH, h = bh % NH;
  const int tid = threadIdx.x, lane = tid & 63, w = tid >> 6;
  const int rl = lane & 15, g = lane >> 4;
  __shared__ __align__(16) unsigned short Kl[128 * 64];     // [kv][d]   16KB
  __shared__ __align__(16) unsigned short Vt[64 * 128];     // [d][kv]   16KB
  __shared__ __align__(16) unsigned short Pl[4][16 * 128];  // per-wave [q][kv] 16KB
  const size_t base = (size_t)b * T * C3;
  const int hq = h * 64, hk = 768 + h * 64, hv = 1536 + h * 64;
  const int qr0 = qt * 64 + w * 16;
  const int qrow = qr0 + rl;  // this lane's q row (swapped layout)

  bf16x8 qf[2];
#pragma unroll
  for (int c = 0; c < 2; ++c)
    qf[c] = *(const bf16x8*)(qkv + base + (size_t)(qr0 + rl) * C3 + hq + 32 * c + 8 * g);

  const int kr = tid >> 1, kh = tid & 1;
  const int va = tid & 31, vdg = tid >> 5;
  const unsigned short* Kg = qkv + base + (size_t)kr * C3 + hk + kh * 32;
  const unsigned short* Vg = qkv + base + (size_t)(4 * va) * C3 + hv + vdg * 8;

  f32x4 o[4];  // o[nf][r] = O^T[d = nf*16 + g*4 + r][q = rl]
  float m_r = -1e30f, s_r = 0.0f;
#pragma unroll
  for (int i = 0; i < 4; ++i) o[i] = 0.0f;

  const int nt2 = (qt + 2) >> 1;  // ceil((qt+1)*64 / 128)
  bf16x8 kp[4], vp[4];
#pragma unroll
  for (int i = 0; i < 4; ++i) kp[i] = *(const bf16x8*)(Kg + i * 8);
#pragma unroll
  for (int i = 0; i < 4; ++i) vp[i] = *(const bf16x8*)(Vg + (size_t)i * C3);

  unsigned short* Pw = Pl[w];

  for (int t = 0; t < nt2; ++t) {
    __syncthreads();  // LDS free (prev tile's compute done)
#pragma unroll
    for (int i = 0; i < 4; ++i)
      *(bf16x8*)((char*)Kl + kr * 128 + (((kh * 4 + i) ^ (kr & 7)) << 4)) = kp[i];
#pragma unroll
    for (int i = 0; i < 8; ++i) {
      const int d = vdg * 8 + i;
      unsigned long long wv =
          (unsigned long long)(unsigned short)vp[0][i] |
          ((unsigned long long)(unsigned short)vp[1][i] << 16) |
          ((unsigned long long)(unsigned short)vp[2][i] << 32) |
          ((unsigned long long)(unsigned short)vp[3][i] << 48);
      *(unsigned long long*)((char*)Vt + d * 256 + (((va >> 1) ^ i) << 4) +
                             (va & 1) * 8) = wv;
    }
    __syncthreads();  // LDS ready
    if (t + 1 < nt2) {
      const unsigned short* nk = Kg + (size_t)(t + 1) * 128 * C3;
      const unsigned short* nv = Vg + (size_t)(t + 1) * 128 * C3;
#pragma unroll
      for (int i = 0; i < 4; ++i) kp[i] = *(const bf16x8*)(nk + i * 8);
#pragma unroll
      for (int i = 0; i < 4; ++i) vp[i] = *(const bf16x8*)(nv + (size_t)i * C3);
    }

    // ---- S^T = K Q^T (swapped, log2 domain): s[ch][r] = S[kv=ch*16+g*4+r][q=rl] ----
    f32x4 s[8];
#pragma unroll
    for (int ch = 0; ch < 8; ++ch) s[ch] = 0.0f;
#pragma unroll
    for (int c = 0; c < 2; ++c)
#pragma unroll
      for (int ch = 0; ch < 8; ++ch) {
        bf16x8 kb = *(const bf16x8*)((char*)Kl + (ch * 16 + rl) * 128 +
                                     ((((c << 2) | g) ^ (rl & 7)) << 4));
        s[ch] = mfma16(kb, qf[c], s[ch]);
      }

    // ---- lane-local softmax (log2 domain) over this lane's 32 kv scores ----
    const bool diag = (t == nt2 - 1);
    const int kv0 = t * 128;
    float mx = -1e30f;
#pragma unroll
    for (int ch = 0; ch < 8; ++ch) {
      if (diag) {
#pragma unroll
        for (int r = 0; r < 4; ++r)
          if (kv0 + ch * 16 + g * 4 + r > qrow) s[ch][r] = -1e30f;
      }
      mx = fmaxf(mx, fmaxf(fmaxf(s[ch][0], s[ch][1]), fmaxf(s[ch][2], s[ch][3])));
    }
    mx = fmaxf(mx, __shfl_xor(mx, 16));
    mx = fmaxf(mx, __shfl_xor(mx, 32));
    // defer-max (T13): rescale only when max grew past THR=8 (log2 units)
    if (!__all(mx - m_r <= 8.0f)) {
      const float mnew = fmaxf(m_r, mx);
      const float fs = exp2f(m_r - mnew);
      s_r *= fs;
#pragma unroll
      for (int nf = 0; nf < 4; ++nf)
#pragma unroll
        for (int r = 0; r < 4; ++r) o[nf][r] *= fs;
      m_r = mnew;
    }
    float rs = 0.0f;
#pragma unroll
    for (int ch = 0; ch < 8; ++ch)
#pragma unroll
      for (int r = 0; r < 4; ++r) {
        const float e = exp2f(s[ch][r] - m_r);  // native v_exp (2^x), no mul
        s[ch][r] = e;
        rs += e;
      }
    rs += __shfl_xor(rs, 16);
    rs += __shfl_xor(rs, 32);
    s_r += rs;

    // ---- write P row q=rl (packed b64, swizzle key rl&7) ----
#pragma unroll
    for (int ch = 0; ch < 8; ++ch) {
      uint2 pk;
      pk.x = (unsigned int)f2bf(s[ch][0]) | ((unsigned int)f2bf(s[ch][1]) << 16);
      pk.y = (unsigned int)f2bf(s[ch][2]) | ((unsigned int)f2bf(s[ch][3]) << 16);
      *(uint2*)((char*)Pw + rl * 256 + (((2 * ch + (g >> 1)) ^ (rl & 7)) << 4) +
                (g & 1) * 8) = pk;
    }

    // ---- O^T += V^T P (swapped): same-wave ds dependency, no barrier ----
#pragma unroll
    for (int kb = 0; kb < 4; ++kb) {
      bf16x8 pa = *(const bf16x8*)((char*)Pw + rl * 256 +
                                   (((kb * 4 + g) ^ (rl & 7)) << 4));
#pragma unroll
      for (int nf = 0; nf < 4; ++nf) {
        bf16x8 vb = *(const bf16x8*)((char*)Vt + (nf * 16 + rl) * 256 +
                                     (((kb * 4 + g) ^ (rl & 7)) << 4));
        o[nf] = mfma16(vb, pa, o[nf]);
      }
    }
  }

  // ---- epilogue ----
  const float inv = 1.0f / s_r;
  const size_t rowb = (size_t)(b * T + qr0 + rl) * 768 + hq;
#pragma unroll
  for (int nf = 0; nf < 4; ++nf) {
    ushort4 oh;
    oh.x = f2bf(o[nf][0] * inv);
    oh.y = f2bf(o[nf][1] * inv);
    oh.z = f2bf(o[nf][2] * inv);
    oh.w = f2bf(o[nf][3] * inv);
    *(ushort4*)(yh + rowb + nf * 16 + g * 4) = oh;
  }
}

// ---------------- host launch ----------------
extern "C" void kernel_launch(void* const* d_in, const int* in_sizes, int n_in,
                              void* d_out, int out_size, void* d_ws, size_t ws_size,
                              hipStream_t stream) {
  const float* x    = (const float*)d_in[0];
  const float* ln1w = (const float*)d_in[1];
  const float* ln1b = (const float*)d_in[2];
  const float* qkvw = (const float*)d_in[3];
  const float* qkvb = (const float*)d_in[4];
  const float* outw = (const float*)d_in[5];
  const float* outb = (const float*)d_in[6];
  const float* fc1w = (const float*)d_in[7];
  const float* fc1b = (const float*)d_in[8];
  const float* fc2w = (const float*)d_in[9];
  const float* fc2b = (const float*)d_in[10];
  float* outp = (float*)d_out;

  char* ws = (char*)d_ws;
  unsigned short* qkvw_h = (unsigned short*)ws;  ws += (size_t)2304 * 768 * 2;
  unsigned short* qkvw_l = (unsigned short*)ws;  ws += (size_t)2304 * 768 * 2;
  unsigned short* outw_h = (unsigned short*)ws;  ws += (size_t)768 * 768 * 2;
  unsigned short* outw_l = (unsigned short*)ws;  ws += (size_t)768 * 768 * 2;
  unsigned short* fc1w_h = (unsigned short*)ws;  ws += (size_t)3072 * 768 * 2;
  unsigned short* fc1w_l = (unsigned short*)ws;  ws += (size_t)3072 * 768 * 2;
  unsigned short* fc2w_h = (unsigned short*)ws;  ws += (size_t)768 * 3072 * 2;
  unsigned short* fc2w_l = (unsigned short*)ws;  ws += (size_t)768 * 3072 * 2;
  unsigned short* h_h    = (unsigned short*)ws;  ws += (size_t)4096 * 768 * 2;
  unsigned short* y_h    = (unsigned short*)ws;  ws += (size_t)4096 * 768 * 2;
  float*          x1     = (float*)ws;           ws += (size_t)4096 * 768 * 4;
  unsigned short* big    = (unsigned short*)ws;  // qkv (18.9MB) then fc1-out g (25.2MB)
  unsigned short* qkv_bf = big;
  unsigned short* g_bf   = big;
  // fc2 split-K partials (bf16, 2 x 4096x768) reuse h_h..y_h (dead after fc1)
  unsigned short* part   = h_h;

  // all 4 weight transposes in one launch
  transpose_all<<<6912, 256, 0, stream>>>(qkvw, outw, fc1w, fc2w,
                                          qkvw_h, qkvw_l, outw_h, outw_l,
                                          fc1w_h, fc1w_l, fc2w_h, fc2w_l);

  // h = LN(x) -> bf16 hi
  ln_hi<<<4096, 192, 0, stream>>>(x, ln1w, ln1b, h_h);
  // qkv = h @ qkv_w + qkv_b  (1-term, bf16 out, Q pre-scaled to log2 domain) — M-major
  gemmT<3, 1, 12, 0><<<dim3(32, 18), 512, 0, stream>>>(h_h, nullptr, qkvw_h, qkvw_l,
                                                       qkvb, nullptr, qkv_bf, 2304, 768);
  // y = attention(qkv), bf16 out — grid (bh, q) for XCD L2 locality
  attn_kernel<<<dim3(24, 32), 256, 0, stream>>>(qkv_bf, y_h);
  // x1 = x + y @ out_w + out_b  (2-term, f32 resid out) — M-major
  gemmT<2, 2, 12, 0><<<dim3(32, 6), 512, 0, stream>>>(y_h, nullptr, outw_h, outw_l,
                                                      outb, x, x1, 768, 768);
  // h = LN(x1) -> bf16 hi
  ln_hi<<<4096, 192, 0, stream>>>(x1, ln1w, ln1b, h_h);
  // g = gelu(h @ fc1_w + fc1_b)  (1-term, fast-gelu bf16 out) — M-major
  gemmT<1, 1, 12, 0><<<dim3(32, 24), 512, 0, stream>>>(h_h, nullptr, fc1w_h, fc1w_l,
                                                       fc1b, nullptr, g_bf, 3072, 768);
  // fc2 split-K by term: z=0 -> g@fc2w_h + bias, z=1 -> g@fc2w_l; bf16 partials
  gemmT<0, 1, 48, 1><<<dim3(32, 6, 2), 512, 0, stream>>>(g_bf, nullptr, fc2w_h, fc2w_l,
                                                         fc2b, nullptr, part, 768, 3072);
  // out = x1 + p0 + p1
  fc2_reduce<<<3072, 256, 0, stream>>>(x1, part, part + (size_t)4096 * 768, outp);
}

// Round 22
// 190.075 us; speedup vs baseline: 1.0528x; 1.0528x over previous
//
#include <hip/hip_runtime.h>
#include <hip/hip_bf16.h>

typedef __attribute__((ext_vector_type(8))) short bf16x8;
typedef __attribute__((ext_vector_type(4))) float f32x4;

__device__ __forceinline__ f32x4 mfma16(bf16x8 a, bf16x8 b, f32x4 c) {
  return __builtin_amdgcn_mfma_f32_16x16x32_bf16(a, b, c, 0, 0, 0);
}

__device__ __forceinline__ void gload_lds16(const void* g, void* l) {
  __builtin_amdgcn_global_load_lds(
      (__attribute__((address_space(1))) void*)(g),
      (__attribute__((address_space(3))) void*)(l), 16, 0, 0);
}

__device__ __forceinline__ unsigned short f2bf(float f) {
  union { __hip_bfloat16 h; unsigned short u; } cv;
  cv.h = __float2bfloat16(f);
  return cv.u;
}

__device__ __forceinline__ float bf2f_(unsigned short u) {
  union { unsigned int i; float f; } c;
  c.i = (unsigned int)u << 16;
  return c.f;
}

__device__ __forceinline__ void split2(float v, unsigned short& hb, unsigned short& lb) {
  __hip_bfloat16 hh = __float2bfloat16(v);
  union { __hip_bfloat16 h; unsigned short u; } cv;
  cv.h = hh;
  hb = cv.u;
  lb = f2bf(v - __bfloat162float(hh));
}

// fast gelu: tanh(u) = (e^{2u}-1)/(e^{2u}+1) via v_exp + v_rcp
__device__ __forceinline__ float gelu_f(float v) {
  float u = 0.7978845608028654f * (v + 0.044715f * v * v * v);
  float t = __expf(2.0f * u);
  float th = (t - 1.0f) * __builtin_amdgcn_rcpf(t + 1.0f);
  return 0.5f * v * (1.0f + th);
}

// ---------------- fused transpose+cast-split for all 4 weights (one launch) ----------------
__global__ __launch_bounds__(256) void transpose_all(
    const float* __restrict__ w0, const float* __restrict__ w1,
    const float* __restrict__ w2, const float* __restrict__ w3,
    unsigned short* __restrict__ h0, unsigned short* __restrict__ l0,
    unsigned short* __restrict__ h1, unsigned short* __restrict__ l1,
    unsigned short* __restrict__ h2, unsigned short* __restrict__ l2,
    unsigned short* __restrict__ h3, unsigned short* __restrict__ l3) {
  __shared__ float tile[32][33];
  const int id = blockIdx.x;
  const float* in;
  unsigned short *oh, *ol;
  int K, N, nx, local;
  if (id < 1728)      { in = w0; oh = h0; ol = l0; K = 768;  N = 2304; nx = 72; local = id; }
  else if (id < 2304) { in = w1; oh = h1; ol = l1; K = 768;  N = 768;  nx = 24; local = id - 1728; }
  else if (id < 4608) { in = w2; oh = h2; ol = l2; K = 768;  N = 3072; nx = 96; local = id - 2304; }
  else                { in = w3; oh = h3; ol = l3; K = 3072; N = 768;  nx = 24; local = id - 4608; }
  const int n0 = (local % nx) * 32, k0 = (local / nx) * 32;
  const int tx = threadIdx.x & 31, ty = threadIdx.x >> 5;  // ty 0..7
#pragma unroll
  for (int i = 0; i < 32; i += 8)
    tile[ty + i][tx] = in[(size_t)(k0 + ty + i) * N + (n0 + tx)];
  __syncthreads();
#pragma unroll
  for (int i = 0; i < 32; i += 8) {
    unsigned short hb, lb;
    split2(tile[tx][ty + i], hb, lb);
    const size_t idx = (size_t)(n0 + ty + i) * K + (k0 + tx);
    oh[idx] = hb;
    ol[idx] = lb;
  }
}

// ---------------- LayerNorm (C=768) f32 -> bf16 (hi only) ----------------
__global__ __launch_bounds__(192) void ln_hi(
    const float* __restrict__ x, const float* __restrict__ w,
    const float* __restrict__ bb, unsigned short* __restrict__ outh) {
  const int row = blockIdx.x;
  const int t = threadIdx.x;  // 0..191, 4 floats each
  const float4 v = ((const float4*)(x + (size_t)row * 768))[t];
  float s = v.x + v.y + v.z + v.w;
  float q = v.x * v.x + v.y * v.y + v.z * v.z + v.w * v.w;
#pragma unroll
  for (int off = 1; off < 64; off <<= 1) {
    s += __shfl_xor(s, off);
    q += __shfl_xor(q, off);
  }
  __shared__ float ss[3], qq[3];
  const int wid = t >> 6;
  if ((t & 63) == 0) { ss[wid] = s; qq[wid] = q; }
  __syncthreads();
  const float S = ss[0] + ss[1] + ss[2];
  const float Q = qq[0] + qq[1] + qq[2];
  const float mu = S * (1.0f / 768.0f);
  const float var = Q * (1.0f / 768.0f) - mu * mu;
  const float rstd = rsqrtf(var + 1e-5f);
  const float4 wv = ((const float4*)w)[t];
  const float4 bv = ((const float4*)bb)[t];
  ushort4 oh;
  oh.x = f2bf((v.x - mu) * rstd * wv.x + bv.x);
  oh.y = f2bf((v.y - mu) * rstd * wv.y + bv.y);
  oh.z = f2bf((v.z - mu) * rstd * wv.z + bv.z);
  oh.w = f2bf((v.w - mu) * rstd * wv.w + bv.w);
  ((ushort4*)(outh + (size_t)row * 768))[t] = oh;
}

// ---------------- fc2 reduce: out = x1 + p0 + p1 (partials bf16, bias folded in p0) ----
__global__ __launch_bounds__(256) void fc2_reduce(
    const float* __restrict__ x1, const unsigned short* __restrict__ p0,
    const unsigned short* __restrict__ p1, float* __restrict__ out) {
  const size_t i = ((size_t)blockIdx.x * 256 + threadIdx.x) * 4;
  const float4 xv = *(const float4*)(x1 + i);
  const ushort4 a = *(const ushort4*)(p0 + i);
  const ushort4 b = *(const ushort4*)(p1 + i);
  float4 o;
  o.x = xv.x + bf2f_(a.x) + bf2f_(b.x);
  o.y = xv.y + bf2f_(a.y) + bf2f_(b.y);
  o.z = xv.z + bf2f_(a.z) + bf2f_(b.z);
  o.w = xv.w + bf2f_(a.w) + bf2f_(b.w);
  *(float4*)(out + i) = o;
}

// ============ 128x128 2-phase GEMM (augmented-K split-bf16), BK=64, 8 waves ============
// M-major grid (XCD = m-block%8). NTERM=1: qkv+fc1 (r19-validated). SPLITK=1: fc2.
// EPI: 0 bf16; 1 gelu+bf16; 2 f32 resid; 3 bf16 with 0.125 scale on cols<768 (Q pre-scale).
template <int EPI, int NTERM, int NKT, int SPLITK>
__global__ __launch_bounds__(512, 2) void gemmT(
    const unsigned short* __restrict__ Ah, const unsigned short* __restrict__ Al,
    const unsigned short* __restrict__ Bh, const unsigned short* __restrict__ Bl,
    const float* __restrict__ bias, const float* __restrict__ resid,
    void* __restrict__ outp, int N, int K) {
  __shared__ __align__(16) char lds[65536];
  const int tid = threadIdx.x;
  const int lane = tid & 63, wid = tid >> 6;
  const int wr = wid >> 1, wc = wid & 1;  // wave -> 32-row x 64-col output region
  const int rl = lane & 15, g = lane >> 4;
  const int m0 = blockIdx.x * 128, n0 = blockIdx.y * 128;  // M-major
  const int NT = NTERM * NKT;

  const int srw = lane >> 3;
  const int csrc = (lane & 7) ^ srw;
  const size_t a_base = (size_t)(m0 + wid * 8 + srw) * K + csrc * 8;
  const size_t b_base = (size_t)(n0 + wid * 8 + srw) * K + csrc * 8;

  auto stageA = [&](int buf, int half, int tile) {
    const int tt = (tile < NT) ? tile : 0;
    const int term = tt / NKT, kc = tt - term * NKT;
    const unsigned short* src = (NTERM == 3 && term == 2) ? Al : Ah;
    const unsigned short* gp = src + a_base + (size_t)half * 64 * K + kc * 64;
    gload_lds16(gp, lds + buf * 16384 + half * 8192 + wid * 1024);
  };
  auto stageB = [&](int buf, int half, int tile) {
    const int tt = (tile < NT) ? tile : 0;
    const int term = tt / NKT, kc = tt - term * NKT;
    const unsigned short* src = (term == 1) ? Bl : Bh;
    if (SPLITK) src = blockIdx.z ? Bl : Bh;
    const unsigned short* gp = src + b_base + (size_t)half * 64 * K + kc * 64;
    gload_lds16(gp, lds + 32768 + buf * 16384 + half * 8192 + wid * 1024);
  };
  auto rdA = [&](int buf, int mf, int s) -> bf16x8 {
    const int row = wr * 32 + mf * 16 + rl;
    const int c = (s * 4 + g) ^ (row & 7);
    return *(const bf16x8*)(lds + buf * 16384 + row * 128 + c * 16);
  };
  auto rdB = [&](int buf, int nfp, int s) -> bf16x8 {
    const int row = wc * 64 + nfp * 16 + rl;
    const int c = (s * 4 + g) ^ (row & 7);
    return *(const bf16x8*)(lds + 32768 + buf * 16384 + row * 128 + c * 16);
  };

  f32x4 acc[2][4];
#pragma unroll
  for (int i = 0; i < 2; ++i)
#pragma unroll
    for (int j = 0; j < 4; ++j) acc[i][j] = 0.0f;

  bf16x8 af[2][2], bfr[2][2];

  stageA(0, 0, 0); stageA(0, 1, 0);
  stageB(0, 0, 0); stageB(0, 1, 0);
  stageA(1, 0, 1); stageA(1, 1, 1);
  asm volatile("s_waitcnt vmcnt(2)" ::: "memory");
  __builtin_amdgcn_s_barrier();

#define TILE(P, T)                                                                \
  {                                                                               \
    _Pragma("unroll") for (int mf = 0; mf < 2; ++mf)                              \
    _Pragma("unroll") for (int s = 0; s < 2; ++s) af[mf][s] = rdA(P, mf, s);      \
    _Pragma("unroll") for (int nf = 0; nf < 2; ++nf)                              \
    _Pragma("unroll") for (int s = 0; s < 2; ++s) bfr[nf][s] = rdB(P, nf, s);     \
    stageB((P) ^ 1, 0, (T) + 1);                                                  \
    stageB((P) ^ 1, 1, (T) + 1);                                                  \
    __builtin_amdgcn_s_barrier();                                                 \
    asm volatile("s_waitcnt lgkmcnt(0)" ::: "memory");                            \
    __builtin_amdgcn_sched_barrier(0);                                            \
    __builtin_amdgcn_s_setprio(1);                                                \
    _Pragma("unroll") for (int mf = 0; mf < 2; ++mf)                              \
    _Pragma("unroll") for (int nf = 0; nf < 2; ++nf)                              \
    _Pragma("unroll") for (int s = 0; s < 2; ++s)                                 \
        acc[mf][nf] = mfma16(af[mf][s], bfr[nf][s], acc[mf][nf]);                 \
    __builtin_amdgcn_s_setprio(0);                                                \
    __builtin_amdgcn_s_barrier();                                                 \
    _Pragma("unroll") for (int nf = 0; nf < 2; ++nf)                              \
    _Pragma("unroll") for (int s = 0; s < 2; ++s) bfr[nf][s] = rdB(P, 2 + nf, s); \
    stageA(P, 0, (T) + 2);                                                        \
    stageA(P, 1, (T) + 2);                                                        \
    __builtin_amdgcn_s_barrier();                                                 \
    asm volatile("s_waitcnt lgkmcnt(0)" ::: "memory");                            \
    __builtin_amdgcn_sched_barrier(0);                                            \
    __builtin_amdgcn_s_setprio(1);                                                \
    _Pragma("unroll") for (int mf = 0; mf < 2; ++mf)                              \
    _Pragma("unroll") for (int nf = 0; nf < 2; ++nf)                              \
    _Pragma("unroll") for (int s = 0; s < 2; ++s)                                 \
        acc[mf][2 + nf] = mfma16(af[mf][s], bfr[nf][s], acc[mf][2 + nf]);         \
    __builtin_amdgcn_s_setprio(0);                                                \
    asm volatile("s_waitcnt vmcnt(2)" ::: "memory");                              \
    __builtin_amdgcn_s_barrier();                                                 \
  }

  for (int t = 0; t < NT; t += 2) {
    TILE(0, t)
    TILE(1, t + 1)
  }
#undef TILE

  __hip_bfloat16* outb16 = (__hip_bfloat16*)outp;
  if (SPLITK)
    outb16 += (size_t)blockIdx.z * (size_t)gridDim.x * 128 * (size_t)N;
  float* outf = (float*)outp;
#pragma unroll
  for (int nfp = 0; nfp < 4; ++nfp) {
    const int col = n0 + wc * 64 + nfp * 16 + rl;
    float bia = bias[col];
    if (SPLITK && blockIdx.z) bia = 0.0f;
#pragma unroll
    for (int mf = 0; mf < 2; ++mf) {
      const int rowb = m0 + wr * 32 + mf * 16 + g * 4;
#pragma unroll
      for (int r = 0; r < 4; ++r) {
        float val = acc[mf][nfp][r] + bia;
        const size_t idx = (size_t)(rowb + r) * N + col;
        if (EPI == 1) val = gelu_f(val);
        if (EPI == 3 && col < 768) val *= 0.125f;  // attention scale folded into Q
        if (EPI == 2)
          outf[idx] = resid[idx] + val;
        else
          outb16[idx] = __float2bfloat16(val);
      }
    }
  }
}

// ---------------- fused causal attention (swapped-QK^T, KVBLK=128, XCD-local grid) ----------------
// r22: exact r19 checkpoint (best verified: attn 57us, VGPR 84). Q pre-scaled by
// 0.125 in qkv epilogue; __expf (fast intrinsic: v_mul+v_exp). libm exp2f variant
// (r20/r21) bloated VGPR 84->112 via its accuracy-guarded expansion — reverted.
__global__ __launch_bounds__(256) void attn_kernel(
    const unsigned short* __restrict__ qkv, unsigned short* __restrict__ yh) {
  const int T = 2048, C3 = 2304, NH = 12;
  const int bh = blockIdx.x;            // 0..23 -> XCD = bh%8
  const int bq = blockIdx.y;            // 0..31
  const int qt = (bq & 1) ? (31 - (bq >> 1)) : (bq >> 1);  // long/short pairing
  const int b = bh / NH, h = bh % NH;
  const int tid = threadIdx.x, lane = tid & 63, w = tid >> 6;
  const int rl = lane & 15, g = lane >> 4;
  __shared__ __align__(16) unsigned short Kl[128 * 64];     // [kv][d]   16KB
  __shared__ __align__(16) unsigned short Vt[64 * 128];     // [d][kv]   16KB
  __shared__ __align__(16) unsigned short Pl[4][16 * 128];  // per-wave [q][kv] 16KB
  const size_t base = (size_t)b * T * C3;
  const int hq = h * 64, hk = 768 + h * 64, hv = 1536 + h * 64;
  const int qr0 = qt * 64 + w * 16;
  const int qrow = qr0 + rl;  // this lane's q row (swapped layout)

  bf16x8 qf[2];
#pragma unroll
  for (int c = 0; c < 2; ++c)
    qf[c] = *(const bf16x8*)(qkv + base + (size_t)(qr0 + rl) * C3 + hq + 32 * c + 8 * g);

  const int kr = tid >> 1, kh = tid & 1;
  const int va = tid & 31, vdg = tid >> 5;
  const unsigned short* Kg = qkv + base + (size_t)kr * C3 + hk + kh * 32;
  const unsigned short* Vg = qkv + base + (size_t)(4 * va) * C3 + hv + vdg * 8;

  f32x4 o[4];  // o[nf][r] = O^T[d = nf*16 + g*4 + r][q = rl]
  float m_r = -1e30f, s_r = 0.0f;
#pragma unroll
  for (int i = 0; i < 4; ++i) o[i] = 0.0f;

  const int nt2 = (qt + 2) >> 1;  // ceil((qt+1)*64 / 128)
  bf16x8 kp[4], vp[4];
#pragma unroll
  for (int i = 0; i < 4; ++i) kp[i] = *(const bf16x8*)(Kg + i * 8);
#pragma unroll
  for (int i = 0; i < 4; ++i) vp[i] = *(const bf16x8*)(Vg + (size_t)i * C3);

  unsigned short* Pw = Pl[w];

  for (int t = 0; t < nt2; ++t) {
    __syncthreads();  // LDS free (prev tile's compute done)
#pragma unroll
    for (int i = 0; i < 4; ++i)
      *(bf16x8*)((char*)Kl + kr * 128 + (((kh * 4 + i) ^ (kr & 7)) << 4)) = kp[i];
#pragma unroll
    for (int i = 0; i < 8; ++i) {
      const int d = vdg * 8 + i;
      unsigned long long wv =
          (unsigned long long)(unsigned short)vp[0][i] |
          ((unsigned long long)(unsigned short)vp[1][i] << 16) |
          ((unsigned long long)(unsigned short)vp[2][i] << 32) |
          ((unsigned long long)(unsigned short)vp[3][i] << 48);
      *(unsigned long long*)((char*)Vt + d * 256 + (((va >> 1) ^ i) << 4) +
                             (va & 1) * 8) = wv;
    }
    __syncthreads();  // LDS ready
    if (t + 1 < nt2) {
      const unsigned short* nk = Kg + (size_t)(t + 1) * 128 * C3;
      const unsigned short* nv = Vg + (size_t)(t + 1) * 128 * C3;
#pragma unroll
      for (int i = 0; i < 4; ++i) kp[i] = *(const bf16x8*)(nk + i * 8);
#pragma unroll
      for (int i = 0; i < 4; ++i) vp[i] = *(const bf16x8*)(nv + (size_t)i * C3);
    }

    // ---- S^T = K Q^T (swapped): s[ch][r] = S[kv=ch*16+g*4+r][q=rl] ----
    f32x4 s[8];
#pragma unroll
    for (int ch = 0; ch < 8; ++ch) s[ch] = 0.0f;
#pragma unroll
    for (int c = 0; c < 2; ++c)
#pragma unroll
      for (int ch = 0; ch < 8; ++ch) {
        bf16x8 kb = *(const bf16x8*)((char*)Kl + (ch * 16 + rl) * 128 +
                                     ((((c << 2) | g) ^ (rl & 7)) << 4));
        s[ch] = mfma16(kb, qf[c], s[ch]);
      }

    // ---- lane-local softmax over this lane's 32 kv scores (q=rl) ----
    const bool diag = (t == nt2 - 1);
    const int kv0 = t * 128;
    float mx = -1e30f;
#pragma unroll
    for (int ch = 0; ch < 8; ++ch)
#pragma unroll
      for (int r = 0; r < 4; ++r) {
        float v = s[ch][r];  // Q pre-scaled in qkv epilogue
        if (diag) v = (kv0 + ch * 16 + g * 4 + r > qrow) ? -1e30f : v;
        s[ch][r] = v;
        mx = fmaxf(mx, v);
      }
    mx = fmaxf(mx, __shfl_xor(mx, 16));
    mx = fmaxf(mx, __shfl_xor(mx, 32));
    // defer-max (T13): rescale only when max grew past THR=8
    if (!__all(mx - m_r <= 8.0f)) {
      const float mnew = fmaxf(m_r, mx);
      const float fs = __expf(m_r - mnew);
      s_r *= fs;
#pragma unroll
      for (int nf = 0; nf < 4; ++nf)
#pragma unroll
        for (int r = 0; r < 4; ++r) o[nf][r] *= fs;
      m_r = mnew;
    }
    float rs = 0.0f;
#pragma unroll
    for (int ch = 0; ch < 8; ++ch)
#pragma unroll
      for (int r = 0; r < 4; ++r) {
        const float e = __expf(s[ch][r] - m_r);
        s[ch][r] = e;  // p stored in place
        rs += e;
      }
    rs += __shfl_xor(rs, 16);
    rs += __shfl_xor(rs, 32);
    s_r += rs;

    // ---- write P row q=rl (packed b64, swizzle key rl&7) ----
#pragma unroll
    for (int ch = 0; ch < 8; ++ch) {
      uint2 pk;
      pk.x = (unsigned int)f2bf(s[ch][0]) | ((unsigned int)f2bf(s[ch][1]) << 16);
      pk.y = (unsigned int)f2bf(s[ch][2]) | ((unsigned int)f2bf(s[ch][3]) << 16);
      *(uint2*)((char*)Pw + rl * 256 + (((2 * ch + (g >> 1)) ^ (rl & 7)) << 4) +
                (g & 1) * 8) = pk;
    }

    // ---- O^T += V^T P (swapped): same-wave ds dependency, no barrier ----
#pragma unroll
    for (int kb = 0; kb < 4; ++kb) {
      bf16x8 pa = *(const bf16x8*)((char*)Pw + rl * 256 +
                                   (((kb * 4 + g) ^ (rl & 7)) << 4));
#pragma unroll
      for (int nf = 0; nf < 4; ++nf) {
        bf16x8 vb = *(const bf16x8*)((char*)Vt + (nf * 16 + rl) * 256 +
                                     (((kb * 4 + g) ^ (rl & 7)) << 4));
        o[nf] = mfma16(vb, pa, o[nf]);
      }
    }
  }

  // ---- epilogue ----
  const float inv = 1.0f / s_r;
  const size_t rowb = (size_t)(b * T + qr0 + rl) * 768 + hq;
#pragma unroll
  for (int nf = 0; nf < 4; ++nf) {
    ushort4 oh;
    oh.x = f2bf(o[nf][0] * inv);
    oh.y = f2bf(o[nf][1] * inv);
    oh.z = f2bf(o[nf][2] * inv);
    oh.w = f2bf(o[nf][3] * inv);
    *(ushort4*)(yh + rowb + nf * 16 + g * 4) = oh;
  }
}

// ---------------- host launch ----------------
extern "C" void kernel_launch(void* const* d_in, const int* in_sizes, int n_in,
                              void* d_out, int out_size, void* d_ws, size_t ws_size,
                              hipStream_t stream) {
  const float* x    = (const float*)d_in[0];
  const float* ln1w = (const float*)d_in[1];
  const float* ln1b = (const float*)d_in[2];
  const float* qkvw = (const float*)d_in[3];
  const float* qkvb = (const float*)d_in[4];
  const float* outw = (const float*)d_in[5];
  const float* outb = (const float*)d_in[6];
  const float* fc1w = (const float*)d_in[7];
  const float* fc1b = (const float*)d_in[8];
  const float* fc2w = (const float*)d_in[9];
  const float* fc2b = (const float*)d_in[10];
  float* outp = (float*)d_out;

  char* ws = (char*)d_ws;
  unsigned short* qkvw_h = (unsigned short*)ws;  ws += (size_t)2304 * 768 * 2;
  unsigned short* qkvw_l = (unsigned short*)ws;  ws += (size_t)2304 * 768 * 2;
  unsigned short* outw_h = (unsigned short*)ws;  ws += (size_t)768 * 768 * 2;
  unsigned short* outw_l = (unsigned short*)ws;  ws += (size_t)768 * 768 * 2;
  unsigned short* fc1w_h = (unsigned short*)ws;  ws += (size_t)3072 * 768 * 2;
  unsigned short* fc1w_l = (unsigned short*)ws;  ws += (size_t)3072 * 768 * 2;
  unsigned short* fc2w_h = (unsigned short*)ws;  ws += (size_t)768 * 3072 * 2;
  unsigned short* fc2w_l = (unsigned short*)ws;  ws += (size_t)768 * 3072 * 2;
  unsigned short* h_h    = (unsigned short*)ws;  ws += (size_t)4096 * 768 * 2;
  unsigned short* y_h    = (unsigned short*)ws;  ws += (size_t)4096 * 768 * 2;
  float*          x1     = (float*)ws;           ws += (size_t)4096 * 768 * 4;
  unsigned short* big    = (unsigned short*)ws;  // qkv (18.9MB) then fc1-out g (25.2MB)
  unsigned short* qkv_bf = big;
  unsigned short* g_bf   = big;
  // fc2 split-K partials (bf16, 2 x 4096x768) reuse h_h..y_h (dead after fc1)
  unsigned short* part   = h_h;

  // all 4 weight transposes in one launch
  transpose_all<<<6912, 256, 0, stream>>>(qkvw, outw, fc1w, fc2w,
                                          qkvw_h, qkvw_l, outw_h, outw_l,
                                          fc1w_h, fc1w_l, fc2w_h, fc2w_l);

  // h = LN(x) -> bf16 hi
  ln_hi<<<4096, 192, 0, stream>>>(x, ln1w, ln1b, h_h);
  // qkv = h @ qkv_w + qkv_b  (1-term, bf16 out, Q pre-scaled by 0.125) — M-major
  gemmT<3, 1, 12, 0><<<dim3(32, 18), 512, 0, stream>>>(h_h, nullptr, qkvw_h, qkvw_l,
                                                       qkvb, nullptr, qkv_bf, 2304, 768);
  // y = attention(qkv), bf16 out — grid (bh, q) for XCD L2 locality
  attn_kernel<<<dim3(24, 32), 256, 0, stream>>>(qkv_bf, y_h);
  // x1 = x + y @ out_w + out_b  (2-term, f32 resid out) — M-major
  gemmT<2, 2, 12, 0><<<dim3(32, 6), 512, 0, stream>>>(y_h, nullptr, outw_h, outw_l,
                                                      outb, x, x1, 768, 768);
  // h = LN(x1) -> bf16 hi
  ln_hi<<<4096, 192, 0, stream>>>(x1, ln1w, ln1b, h_h);
  // g = gelu(h @ fc1_w + fc1_b)  (1-term, fast-gelu bf16 out) — M-major
  gemmT<1, 1, 12, 0><<<dim3(32, 24), 512, 0, stream>>>(h_h, nullptr, fc1w_h, fc1w_l,
                                                       fc1b, nullptr, g_bf, 3072, 768);
  // fc2 split-K by term: z=0 -> g@fc2w_h + bias, z=1 -> g@fc2w_l; bf16 partials
  gemmT<0, 1, 48, 1><<<dim3(32, 6, 2), 512, 0, stream>>>(g_bf, nullptr, fc2w_h, fc2w_l,
                                                         fc2b, nullptr, part, 768, 3072);
  // out = x1 + p0 + p1
  fc2_reduce<<<3072, 256, 0, stream>>>(x1, part, part + (size_t)4096 * 768, outp);
}

// Round 23
// 163.787 us; speedup vs baseline: 1.2218x; 1.1605x over previous
//
#include <hip/hip_runtime.h>
#include <hip/hip_bf16.h>

typedef __attribute__((ext_vector_type(8))) short bf16x8;
typedef __attribute__((ext_vector_type(4))) float f32x4;

__device__ __forceinline__ f32x4 mfma16(bf16x8 a, bf16x8 b, f32x4 c) {
  return __builtin_amdgcn_mfma_f32_16x16x32_bf16(a, b, c, 0, 0, 0);
}

__device__ __forceinline__ void gload_lds16(const void* g, void* l) {
  __builtin_amdgcn_global_load_lds(
      (__attribute__((address_space(1))) void*)(g),
      (__attribute__((address_space(3))) void*)(l), 16, 0, 0);
}

__device__ __forceinline__ unsigned short f2bf(float f) {
  union { __hip_bfloat16 h; unsigned short u; } cv;
  cv.h = __float2bfloat16(f);
  return cv.u;
}

__device__ __forceinline__ float bf2f_(unsigned short u) {
  union { unsigned int i; float f; } c;
  c.i = (unsigned int)u << 16;
  return c.f;
}

__device__ __forceinline__ void split2(float v, unsigned short& hb, unsigned short& lb) {
  __hip_bfloat16 hh = __float2bfloat16(v);
  union { __hip_bfloat16 h; unsigned short u; } cv;
  cv.h = hh;
  hb = cv.u;
  lb = f2bf(v - __bfloat162float(hh));
}

// fast gelu: tanh(u) = (e^{2u}-1)/(e^{2u}+1) via v_exp + v_rcp
__device__ __forceinline__ float gelu_f(float v) {
  float u = 0.7978845608028654f * (v + 0.044715f * v * v * v);
  float t = __expf(2.0f * u);
  float th = (t - 1.0f) * __builtin_amdgcn_rcpf(t + 1.0f);
  return 0.5f * v * (1.0f + th);
}

// ---------------- fused transpose+cast-split for all 4 weights (one launch) ----------------
__global__ __launch_bounds__(256) void transpose_all(
    const float* __restrict__ w0, const float* __restrict__ w1,
    const float* __restrict__ w2, const float* __restrict__ w3,
    unsigned short* __restrict__ h0, unsigned short* __restrict__ l0,
    unsigned short* __restrict__ h1, unsigned short* __restrict__ l1,
    unsigned short* __restrict__ h2, unsigned short* __restrict__ l2,
    unsigned short* __restrict__ h3, unsigned short* __restrict__ l3) {
  __shared__ float tile[32][33];
  const int id = blockIdx.x;
  const float* in;
  unsigned short *oh, *ol;
  int K, N, nx, local;
  if (id < 1728)      { in = w0; oh = h0; ol = l0; K = 768;  N = 2304; nx = 72; local = id; }
  else if (id < 2304) { in = w1; oh = h1; ol = l1; K = 768;  N = 768;  nx = 24; local = id - 1728; }
  else if (id < 4608) { in = w2; oh = h2; ol = l2; K = 768;  N = 3072; nx = 96; local = id - 2304; }
  else                { in = w3; oh = h3; ol = l3; K = 3072; N = 768;  nx = 24; local = id - 4608; }
  const int n0 = (local % nx) * 32, k0 = (local / nx) * 32;
  const int tx = threadIdx.x & 31, ty = threadIdx.x >> 5;  // ty 0..7
#pragma unroll
  for (int i = 0; i < 32; i += 8)
    tile[ty + i][tx] = in[(size_t)(k0 + ty + i) * N + (n0 + tx)];
  __syncthreads();
#pragma unroll
  for (int i = 0; i < 32; i += 8) {
    unsigned short hb, lb;
    split2(tile[tx][ty + i], hb, lb);
    const size_t idx = (size_t)(n0 + ty + i) * K + (k0 + tx);
    oh[idx] = hb;
    ol[idx] = lb;
  }
}

// ---------------- LayerNorm (C=768) f32 -> bf16 (hi only) ----------------
__global__ __launch_bounds__(192) void ln_hi(
    const float* __restrict__ x, const float* __restrict__ w,
    const float* __restrict__ bb, unsigned short* __restrict__ outh) {
  const int row = blockIdx.x;
  const int t = threadIdx.x;  // 0..191, 4 floats each
  const float4 v = ((const float4*)(x + (size_t)row * 768))[t];
  float s = v.x + v.y + v.z + v.w;
  float q = v.x * v.x + v.y * v.y + v.z * v.z + v.w * v.w;
#pragma unroll
  for (int off = 1; off < 64; off <<= 1) {
    s += __shfl_xor(s, off);
    q += __shfl_xor(q, off);
  }
  __shared__ float ss[3], qq[3];
  const int wid = t >> 6;
  if ((t & 63) == 0) { ss[wid] = s; qq[wid] = q; }
  __syncthreads();
  const float S = ss[0] + ss[1] + ss[2];
  const float Q = qq[0] + qq[1] + qq[2];
  const float mu = S * (1.0f / 768.0f);
  const float var = Q * (1.0f / 768.0f) - mu * mu;
  const float rstd = rsqrtf(var + 1e-5f);
  const float4 wv = ((const float4*)w)[t];
  const float4 bv = ((const float4*)bb)[t];
  ushort4 oh;
  oh.x = f2bf((v.x - mu) * rstd * wv.x + bv.x);
  oh.y = f2bf((v.y - mu) * rstd * wv.y + bv.y);
  oh.z = f2bf((v.z - mu) * rstd * wv.z + bv.z);
  oh.w = f2bf((v.w - mu) * rstd * wv.w + bv.w);
  ((ushort4*)(outh + (size_t)row * 768))[t] = oh;
}

// ---------------- fc2 reduce: out = x1 + p0 + p1 (partials bf16, bias folded in p0) ----
__global__ __launch_bounds__(256) void fc2_reduce(
    const float* __restrict__ x1, const unsigned short* __restrict__ p0,
    const unsigned short* __restrict__ p1, float* __restrict__ out) {
  const size_t i = ((size_t)blockIdx.x * 256 + threadIdx.x) * 4;
  const float4 xv = *(const float4*)(x1 + i);
  const ushort4 a = *(const ushort4*)(p0 + i);
  const ushort4 b = *(const ushort4*)(p1 + i);
  float4 o;
  o.x = xv.x + bf2f_(a.x) + bf2f_(b.x);
  o.y = xv.y + bf2f_(a.y) + bf2f_(b.y);
  o.z = xv.z + bf2f_(a.z) + bf2f_(b.z);
  o.w = xv.w + bf2f_(a.w) + bf2f_(b.w);
  *(float4*)(out + i) = o;
}

// ============ 128x128 2-phase GEMM (augmented-K split-bf16), BK=64, 8 waves ============
// M-major grid (XCD = m-block%8). NTERM=1: qkv/proj/fc1/fc2 (r19/r23-validated:
// absmax pinned at 0.03125 through every lo-term drop — binding error is elsewhere).
// SPLITK=1 (r23): z in {0,1} computes K-chunk z*NKT*64..+NKT*64 of the HI-weight
// product (bf16 partials, bias on z=0) — halves fc2's serial K-chain at 384 blocks.
// EPI: 0 bf16; 1 gelu+bf16; 2 f32 resid; 3 bf16 with 0.125 scale on cols<768.
template <int EPI, int NTERM, int NKT, int SPLITK>
__global__ __launch_bounds__(512, 2) void gemmT(
    const unsigned short* __restrict__ Ah, const unsigned short* __restrict__ Al,
    const unsigned short* __restrict__ Bh, const unsigned short* __restrict__ Bl,
    const float* __restrict__ bias, const float* __restrict__ resid,
    void* __restrict__ outp, int N, int K) {
  __shared__ __align__(16) char lds[65536];
  const int tid = threadIdx.x;
  const int lane = tid & 63, wid = tid >> 6;
  const int wr = wid >> 1, wc = wid & 1;  // wave -> 32-row x 64-col output region
  const int rl = lane & 15, g = lane >> 4;
  const int m0 = blockIdx.x * 128, n0 = blockIdx.y * 128;  // M-major
  const int NT = NTERM * NKT;
  const int kz = SPLITK ? (int)blockIdx.z * (NKT * 64) : 0;  // K-chunk offset

  const int srw = lane >> 3;
  const int csrc = (lane & 7) ^ srw;
  const size_t a_base = (size_t)(m0 + wid * 8 + srw) * K + csrc * 8;
  const size_t b_base = (size_t)(n0 + wid * 8 + srw) * K + csrc * 8;

  auto stageA = [&](int buf, int half, int tile) {
    const int tt = (tile < NT) ? tile : 0;
    const int term = tt / NKT, kc = tt - term * NKT;
    const unsigned short* src = (NTERM == 3 && term == 2) ? Al : Ah;
    const unsigned short* gp = src + a_base + (size_t)half * 64 * K + kc * 64 + kz;
    gload_lds16(gp, lds + buf * 16384 + half * 8192 + wid * 1024);
  };
  auto stageB = [&](int buf, int half, int tile) {
    const int tt = (tile < NT) ? tile : 0;
    const int term = tt / NKT, kc = tt - term * NKT;
    const unsigned short* src = (term == 1) ? Bl : Bh;
    const unsigned short* gp = src + b_base + (size_t)half * 64 * K + kc * 64 + kz;
    gload_lds16(gp, lds + 32768 + buf * 16384 + half * 8192 + wid * 1024);
  };
  auto rdA = [&](int buf, int mf, int s) -> bf16x8 {
    const int row = wr * 32 + mf * 16 + rl;
    const int c = (s * 4 + g) ^ (row & 7);
    return *(const bf16x8*)(lds + buf * 16384 + row * 128 + c * 16);
  };
  auto rdB = [&](int buf, int nfp, int s) -> bf16x8 {
    const int row = wc * 64 + nfp * 16 + rl;
    const int c = (s * 4 + g) ^ (row & 7);
    return *(const bf16x8*)(lds + 32768 + buf * 16384 + row * 128 + c * 16);
  };

  f32x4 acc[2][4];
#pragma unroll
  for (int i = 0; i < 2; ++i)
#pragma unroll
    for (int j = 0; j < 4; ++j) acc[i][j] = 0.0f;

  bf16x8 af[2][2], bfr[2][2];

  stageA(0, 0, 0); stageA(0, 1, 0);
  stageB(0, 0, 0); stageB(0, 1, 0);
  stageA(1, 0, 1); stageA(1, 1, 1);
  asm volatile("s_waitcnt vmcnt(2)" ::: "memory");
  __builtin_amdgcn_s_barrier();

#define TILE(P, T)                                                                \
  {                                                                               \
    _Pragma("unroll") for (int mf = 0; mf < 2; ++mf)                              \
    _Pragma("unroll") for (int s = 0; s < 2; ++s) af[mf][s] = rdA(P, mf, s);      \
    _Pragma("unroll") for (int nf = 0; nf < 2; ++nf)                              \
    _Pragma("unroll") for (int s = 0; s < 2; ++s) bfr[nf][s] = rdB(P, nf, s);     \
    stageB((P) ^ 1, 0, (T) + 1);                                                  \
    stageB((P) ^ 1, 1, (T) + 1);                                                  \
    __builtin_amdgcn_s_barrier();                                                 \
    asm volatile("s_waitcnt lgkmcnt(0)" ::: "memory");                            \
    __builtin_amdgcn_sched_barrier(0);                                            \
    __builtin_amdgcn_s_setprio(1);                                                \
    _Pragma("unroll") for (int mf = 0; mf < 2; ++mf)                              \
    _Pragma("unroll") for (int nf = 0; nf < 2; ++nf)                              \
    _Pragma("unroll") for (int s = 0; s < 2; ++s)                                 \
        acc[mf][nf] = mfma16(af[mf][s], bfr[nf][s], acc[mf][nf]);                 \
    __builtin_amdgcn_s_setprio(0);                                                \
    __builtin_amdgcn_s_barrier();                                                 \
    _Pragma("unroll") for (int nf = 0; nf < 2; ++nf)                              \
    _Pragma("unroll") for (int s = 0; s < 2; ++s) bfr[nf][s] = rdB(P, 2 + nf, s); \
    stageA(P, 0, (T) + 2);                                                        \
    stageA(P, 1, (T) + 2);                                                        \
    __builtin_amdgcn_s_barrier();                                                 \
    asm volatile("s_waitcnt lgkmcnt(0)" ::: "memory");                            \
    __builtin_amdgcn_sched_barrier(0);                                            \
    __builtin_amdgcn_s_setprio(1);                                                \
    _Pragma("unroll") for (int mf = 0; mf < 2; ++mf)                              \
    _Pragma("unroll") for (int nf = 0; nf < 2; ++nf)                              \
    _Pragma("unroll") for (int s = 0; s < 2; ++s)                                 \
        acc[mf][2 + nf] = mfma16(af[mf][s], bfr[nf][s], acc[mf][2 + nf]);         \
    __builtin_amdgcn_s_setprio(0);                                                \
    asm volatile("s_waitcnt vmcnt(2)" ::: "memory");                              \
    __builtin_amdgcn_s_barrier();                                                 \
  }

  for (int t = 0; t < NT; t += 2) {
    TILE(0, t)
    TILE(1, t + 1)
  }
#undef TILE

  __hip_bfloat16* outb16 = (__hip_bfloat16*)outp;
  if (SPLITK)
    outb16 += (size_t)blockIdx.z * (size_t)gridDim.x * 128 * (size_t)N;
  float* outf = (float*)outp;
#pragma unroll
  for (int nfp = 0; nfp < 4; ++nfp) {
    const int col = n0 + wc * 64 + nfp * 16 + rl;
    float bia = bias[col];
    if (SPLITK && blockIdx.z) bia = 0.0f;
#pragma unroll
    for (int mf = 0; mf < 2; ++mf) {
      const int rowb = m0 + wr * 32 + mf * 16 + g * 4;
#pragma unroll
      for (int r = 0; r < 4; ++r) {
        float val = acc[mf][nfp][r] + bia;
        const size_t idx = (size_t)(rowb + r) * N + col;
        if (EPI == 1) val = gelu_f(val);
        if (EPI == 3 && col < 768) val *= 0.125f;  // attention scale folded into Q
        if (EPI == 2)
          outf[idx] = resid[idx] + val;
        else
          outb16[idx] = __float2bfloat16(val);
      }
    }
  }
}

// ---------------- fused causal attention (swapped-QK^T, KVBLK=128, XCD-local grid) ----------------
// r19 checkpoint structure (best verified: 57us, VGPR 84). Q pre-scaled by 0.125.
__global__ __launch_bounds__(256) void attn_kernel(
    const unsigned short* __restrict__ qkv, unsigned short* __restrict__ yh) {
  const int T = 2048, C3 = 2304, NH = 12;
  const int bh = blockIdx.x;            // 0..23 -> XCD = bh%8
  const int bq = blockIdx.y;            // 0..31
  const int qt = (bq & 1) ? (31 - (bq >> 1)) : (bq >> 1);  // long/short pairing
  const int b = bh / NH, h = bh % NH;
  const int tid = threadIdx.x, lane = tid & 63, w = tid >> 6;
  const int rl = lane & 15, g = lane >> 4;
  __shared__ __align__(16) unsigned short Kl[128 * 64];     // [kv][d]   16KB
  __shared__ __align__(16) unsigned short Vt[64 * 128];     // [d][kv]   16KB
  __shared__ __align__(16) unsigned short Pl[4][16 * 128];  // per-wave [q][kv] 16KB
  const size_t base = (size_t)b * T * C3;
  const int hq = h * 64, hk = 768 + h * 64, hv = 1536 + h * 64;
  const int qr0 = qt * 64 + w * 16;
  const int qrow = qr0 + rl;  // this lane's q row (swapped layout)

  bf16x8 qf[2];
#pragma unroll
  for (int c = 0; c < 2; ++c)
    qf[c] = *(const bf16x8*)(qkv + base + (size_t)(qr0 + rl) * C3 + hq + 32 * c + 8 * g);

  const int kr = tid >> 1, kh = tid & 1;
  const int va = tid & 31, vdg = tid >> 5;
  const unsigned short* Kg = qkv + base + (size_t)kr * C3 + hk + kh * 32;
  const unsigned short* Vg = qkv + base + (size_t)(4 * va) * C3 + hv + vdg * 8;

  f32x4 o[4];  // o[nf][r] = O^T[d = nf*16 + g*4 + r][q = rl]
  float m_r = -1e30f, s_r = 0.0f;
#pragma unroll
  for (int i = 0; i < 4; ++i) o[i] = 0.0f;

  const int nt2 = (qt + 2) >> 1;  // ceil((qt+1)*64 / 128)
  bf16x8 kp[4], vp[4];
#pragma unroll
  for (int i = 0; i < 4; ++i) kp[i] = *(const bf16x8*)(Kg + i * 8);
#pragma unroll
  for (int i = 0; i < 4; ++i) vp[i] = *(const bf16x8*)(Vg + (size_t)i * C3);

  unsigned short* Pw = Pl[w];

  for (int t = 0; t < nt2; ++t) {
    __syncthreads();  // LDS free (prev tile's compute done)
#pragma unroll
    for (int i = 0; i < 4; ++i)
      *(bf16x8*)((char*)Kl + kr * 128 + (((kh * 4 + i) ^ (kr & 7)) << 4)) = kp[i];
#pragma unroll
    for (int i = 0; i < 8; ++i) {
      const int d = vdg * 8 + i;
      unsigned long long wv =
          (unsigned long long)(unsigned short)vp[0][i] |
          ((unsigned long long)(unsigned short)vp[1][i] << 16) |
          ((unsigned long long)(unsigned short)vp[2][i] << 32) |
          ((unsigned long long)(unsigned short)vp[3][i] << 48);
      *(unsigned long long*)((char*)Vt + d * 256 + (((va >> 1) ^ i) << 4) +
                             (va & 1) * 8) = wv;
    }
    __syncthreads();  // LDS ready
    if (t + 1 < nt2) {
      const unsigned short* nk = Kg + (size_t)(t + 1) * 128 * C3;
      const unsigned short* nv = Vg + (size_t)(t + 1) * 128 * C3;
#pragma unroll
      for (int i = 0; i < 4; ++i) kp[i] = *(const bf16x8*)(nk + i * 8);
#pragma unroll
      for (int i = 0; i < 4; ++i) vp[i] = *(const bf16x8*)(nv + (size_t)i * C3);
    }

    // ---- S^T = K Q^T (swapped): s[ch][r] = S[kv=ch*16+g*4+r][q=rl] ----
    f32x4 s[8];
#pragma unroll
    for (int ch = 0; ch < 8; ++ch) s[ch] = 0.0f;
#pragma unroll
    for (int c = 0; c < 2; ++c)
#pragma unroll
      for (int ch = 0; ch < 8; ++ch) {
        bf16x8 kb = *(const bf16x8*)((char*)Kl + (ch * 16 + rl) * 128 +
                                     ((((c << 2) | g) ^ (rl & 7)) << 4));
        s[ch] = mfma16(kb, qf[c], s[ch]);
      }

    // ---- lane-local softmax over this lane's 32 kv scores (q=rl) ----
    const bool diag = (t == nt2 - 1);
    const int kv0 = t * 128;
    float mx = -1e30f;
#pragma unroll
    for (int ch = 0; ch < 8; ++ch)
#pragma unroll
      for (int r = 0; r < 4; ++r) {
        float v = s[ch][r];  // Q pre-scaled in qkv epilogue
        if (diag) v = (kv0 + ch * 16 + g * 4 + r > qrow) ? -1e30f : v;
        s[ch][r] = v;
        mx = fmaxf(mx, v);
      }
    mx = fmaxf(mx, __shfl_xor(mx, 16));
    mx = fmaxf(mx, __shfl_xor(mx, 32));
    // defer-max (T13): rescale only when max grew past THR=8
    if (!__all(mx - m_r <= 8.0f)) {
      const float mnew = fmaxf(m_r, mx);
      const float fs = __expf(m_r - mnew);
      s_r *= fs;
#pragma unroll
      for (int nf = 0; nf < 4; ++nf)
#pragma unroll
        for (int r = 0; r < 4; ++r) o[nf][r] *= fs;
      m_r = mnew;
    }
    float rs = 0.0f;
#pragma unroll
    for (int ch = 0; ch < 8; ++ch)
#pragma unroll
      for (int r = 0; r < 4; ++r) {
        const float e = __expf(s[ch][r] - m_r);
        s[ch][r] = e;  // p stored in place
        rs += e;
      }
    rs += __shfl_xor(rs, 16);
    rs += __shfl_xor(rs, 32);
    s_r += rs;

    // ---- write P row q=rl (packed b64, swizzle key rl&7) ----
#pragma unroll
    for (int ch = 0; ch < 8; ++ch) {
      uint2 pk;
      pk.x = (unsigned int)f2bf(s[ch][0]) | ((unsigned int)f2bf(s[ch][1]) << 16);
      pk.y = (unsigned int)f2bf(s[ch][2]) | ((unsigned int)f2bf(s[ch][3]) << 16);
      *(uint2*)((char*)Pw + rl * 256 + (((2 * ch + (g >> 1)) ^ (rl & 7)) << 4) +
                (g & 1) * 8) = pk;
    }

    // ---- O^T += V^T P (swapped): same-wave ds dependency, no barrier ----
#pragma unroll
    for (int kb = 0; kb < 4; ++kb) {
      bf16x8 pa = *(const bf16x8*)((char*)Pw + rl * 256 +
                                   (((kb * 4 + g) ^ (rl & 7)) << 4));
#pragma unroll
      for (int nf = 0; nf < 4; ++nf) {
        bf16x8 vb = *(const bf16x8*)((char*)Vt + (nf * 16 + rl) * 256 +
                                     (((kb * 4 + g) ^ (rl & 7)) << 4));
        o[nf] = mfma16(vb, pa, o[nf]);
      }
    }
  }

  // ---- epilogue ----
  const float inv = 1.0f / s_r;
  const size_t rowb = (size_t)(b * T + qr0 + rl) * 768 + hq;
#pragma unroll
  for (int nf = 0; nf < 4; ++nf) {
    ushort4 oh;
    oh.x = f2bf(o[nf][0] * inv);
    oh.y = f2bf(o[nf][1] * inv);
    oh.z = f2bf(o[nf][2] * inv);
    oh.w = f2bf(o[nf][3] * inv);
    *(ushort4*)(yh + rowb + nf * 16 + g * 4) = oh;
  }
}

// ---------------- host launch ----------------
extern "C" void kernel_launch(void* const* d_in, const int* in_sizes, int n_in,
                              void* d_out, int out_size, void* d_ws, size_t ws_size,
                              hipStream_t stream) {
  const float* x    = (const float*)d_in[0];
  const float* ln1w = (const float*)d_in[1];
  const float* ln1b = (const float*)d_in[2];
  const float* qkvw = (const float*)d_in[3];
  const float* qkvb = (const float*)d_in[4];
  const float* outw = (const float*)d_in[5];
  const float* outb = (const float*)d_in[6];
  const float* fc1w = (const float*)d_in[7];
  const float* fc1b = (const float*)d_in[8];
  const float* fc2w = (const float*)d_in[9];
  const float* fc2b = (const float*)d_in[10];
  float* outp = (float*)d_out;

  char* ws = (char*)d_ws;
  unsigned short* qkvw_h = (unsigned short*)ws;  ws += (size_t)2304 * 768 * 2;
  unsigned short* qkvw_l = (unsigned short*)ws;  ws += (size_t)2304 * 768 * 2;
  unsigned short* outw_h = (unsigned short*)ws;  ws += (size_t)768 * 768 * 2;
  unsigned short* outw_l = (unsigned short*)ws;  ws += (size_t)768 * 768 * 2;
  unsigned short* fc1w_h = (unsigned short*)ws;  ws += (size_t)3072 * 768 * 2;
  unsigned short* fc1w_l = (unsigned short*)ws;  ws += (size_t)3072 * 768 * 2;
  unsigned short* fc2w_h = (unsigned short*)ws;  ws += (size_t)768 * 3072 * 2;
  unsigned short* fc2w_l = (unsigned short*)ws;  ws += (size_t)768 * 3072 * 2;
  unsigned short* h_h    = (unsigned short*)ws;  ws += (size_t)4096 * 768 * 2;
  unsigned short* y_h    = (unsigned short*)ws;  ws += (size_t)4096 * 768 * 2;
  float*          x1     = (float*)ws;           ws += (size_t)4096 * 768 * 4;
  unsigned short* big    = (unsigned short*)ws;  // qkv (18.9MB) then fc1-out g (25.2MB)
  unsigned short* qkv_bf = big;
  unsigned short* g_bf   = big;
  // fc2 split-K partials (bf16, 2 x 4096x768) reuse h_h..y_h (dead after fc1)
  unsigned short* part   = h_h;

  // all 4 weight transposes in one launch
  transpose_all<<<6912, 256, 0, stream>>>(qkvw, outw, fc1w, fc2w,
                                          qkvw_h, qkvw_l, outw_h, outw_l,
                                          fc1w_h, fc1w_l, fc2w_h, fc2w_l);

  // h = LN(x) -> bf16 hi
  ln_hi<<<4096, 192, 0, stream>>>(x, ln1w, ln1b, h_h);
  // qkv = h @ qkv_w + qkv_b  (1-term, bf16 out, Q pre-scaled by 0.125) — M-major
  gemmT<3, 1, 12, 0><<<dim3(32, 18), 512, 0, stream>>>(h_h, nullptr, qkvw_h, qkvw_l,
                                                       qkvb, nullptr, qkv_bf, 2304, 768);
  // y = attention(qkv), bf16 out — grid (bh, q) for XCD L2 locality
  attn_kernel<<<dim3(24, 32), 256, 0, stream>>>(qkv_bf, y_h);
  // x1 = x + y @ out_w + out_b  (1-term, f32 resid out) — M-major
  gemmT<2, 1, 12, 0><<<dim3(32, 6), 512, 0, stream>>>(y_h, nullptr, outw_h, outw_l,
                                                      outb, x, x1, 768, 768);
  // h = LN(x1) -> bf16 hi
  ln_hi<<<4096, 192, 0, stream>>>(x1, ln1w, ln1b, h_h);
  // g = gelu(h @ fc1_w + fc1_b)  (1-term, fast-gelu bf16 out) — M-major
  gemmT<1, 1, 12, 0><<<dim3(32, 24), 512, 0, stream>>>(h_h, nullptr, fc1w_h, fc1w_l,
                                                       fc1b, nullptr, g_bf, 3072, 768);
  // fc2: 1-term, split-K over K-halves (z=0: K 0..1535 +bias; z=1: K 1536..3071)
  gemmT<0, 1, 24, 1><<<dim3(32, 6, 2), 512, 0, stream>>>(g_bf, nullptr, fc2w_h, fc2w_l,
                                                         fc2b, nullptr, part, 768, 3072);
  // out = x1 + p0 + p1
  fc2_reduce<<<3072, 256, 0, stream>>>(x1, part, part + (size_t)4096 * 768, outp);
}

// Round 24
// 162.250 us; speedup vs baseline: 1.2333x; 1.0095x over previous
//
#include <hip/hip_runtime.h>
#include <hip/hip_bf16.h>

typedef __attribute__((ext_vector_type(8))) short bf16x8;
typedef __attribute__((ext_vector_type(4))) float f32x4;

__device__ __forceinline__ f32x4 mfma16(bf16x8 a, bf16x8 b, f32x4 c) {
  return __builtin_amdgcn_mfma_f32_16x16x32_bf16(a, b, c, 0, 0, 0);
}

__device__ __forceinline__ void gload_lds16(const void* g, void* l) {
  __builtin_amdgcn_global_load_lds(
      (__attribute__((address_space(1))) void*)(g),
      (__attribute__((address_space(3))) void*)(l), 16, 0, 0);
}

__device__ __forceinline__ unsigned short f2bf(float f) {
  union { __hip_bfloat16 h; unsigned short u; } cv;
  cv.h = __float2bfloat16(f);
  return cv.u;
}

__device__ __forceinline__ float bf2f_(unsigned short u) {
  union { unsigned int i; float f; } c;
  c.i = (unsigned int)u << 16;
  return c.f;
}

// fast gelu: tanh(u) = (e^{2u}-1)/(e^{2u}+1) via v_exp + v_rcp
__device__ __forceinline__ float gelu_f(float v) {
  float u = 0.7978845608028654f * (v + 0.044715f * v * v * v);
  float t = __expf(2.0f * u);
  float th = (t - 1.0f) * __builtin_amdgcn_rcpf(t + 1.0f);
  return 0.5f * v * (1.0f + th);
}

// ---------------- fused transpose+cast (HI ONLY) for all 4 weights (one launch) ----------
// r24: all GEMMs are 1-term (r23) -> lo arrays were dead; drop their compute+writes.
__global__ __launch_bounds__(256) void transpose_all(
    const float* __restrict__ w0, const float* __restrict__ w1,
    const float* __restrict__ w2, const float* __restrict__ w3,
    unsigned short* __restrict__ h0, unsigned short* __restrict__ h1,
    unsigned short* __restrict__ h2, unsigned short* __restrict__ h3) {
  __shared__ float tile[32][33];
  const int id = blockIdx.x;
  const float* in;
  unsigned short* oh;
  int K, N, nx, local;
  if (id < 1728)      { in = w0; oh = h0; K = 768;  N = 2304; nx = 72; local = id; }
  else if (id < 2304) { in = w1; oh = h1; K = 768;  N = 768;  nx = 24; local = id - 1728; }
  else if (id < 4608) { in = w2; oh = h2; K = 768;  N = 3072; nx = 96; local = id - 2304; }
  else                { in = w3; oh = h3; K = 3072; N = 768;  nx = 24; local = id - 4608; }
  const int n0 = (local % nx) * 32, k0 = (local / nx) * 32;
  const int tx = threadIdx.x & 31, ty = threadIdx.x >> 5;  // ty 0..7
#pragma unroll
  for (int i = 0; i < 32; i += 8)
    tile[ty + i][tx] = in[(size_t)(k0 + ty + i) * N + (n0 + tx)];
  __syncthreads();
#pragma unroll
  for (int i = 0; i < 32; i += 8)
    oh[(size_t)(n0 + ty + i) * K + (k0 + tx)] = f2bf(tile[tx][ty + i]);
}

// ---------------- LayerNorm (C=768) f32 -> bf16 (hi only) ----------------
__global__ __launch_bounds__(192) void ln_hi(
    const float* __restrict__ x, const float* __restrict__ w,
    const float* __restrict__ bb, unsigned short* __restrict__ outh) {
  const int row = blockIdx.x;
  const int t = threadIdx.x;  // 0..191, 4 floats each
  const float4 v = ((const float4*)(x + (size_t)row * 768))[t];
  float s = v.x + v.y + v.z + v.w;
  float q = v.x * v.x + v.y * v.y + v.z * v.z + v.w * v.w;
#pragma unroll
  for (int off = 1; off < 64; off <<= 1) {
    s += __shfl_xor(s, off);
    q += __shfl_xor(q, off);
  }
  __shared__ float ss[3], qq[3];
  const int wid = t >> 6;
  if ((t & 63) == 0) { ss[wid] = s; qq[wid] = q; }
  __syncthreads();
  const float S = ss[0] + ss[1] + ss[2];
  const float Q = qq[0] + qq[1] + qq[2];
  const float mu = S * (1.0f / 768.0f);
  const float var = Q * (1.0f / 768.0f) - mu * mu;
  const float rstd = rsqrtf(var + 1e-5f);
  const float4 wv = ((const float4*)w)[t];
  const float4 bv = ((const float4*)bb)[t];
  ushort4 oh;
  oh.x = f2bf((v.x - mu) * rstd * wv.x + bv.x);
  oh.y = f2bf((v.y - mu) * rstd * wv.y + bv.y);
  oh.z = f2bf((v.z - mu) * rstd * wv.z + bv.z);
  oh.w = f2bf((v.w - mu) * rstd * wv.w + bv.w);
  ((ushort4*)(outh + (size_t)row * 768))[t] = oh;
}

// ---------------- fc2 reduce: out = x1 + p0 + p1 (partials bf16, bias folded in p0) ----
__global__ __launch_bounds__(256) void fc2_reduce(
    const float* __restrict__ x1, const unsigned short* __restrict__ p0,
    const unsigned short* __restrict__ p1, float* __restrict__ out) {
  const size_t i = ((size_t)blockIdx.x * 256 + threadIdx.x) * 4;
  const float4 xv = *(const float4*)(x1 + i);
  const ushort4 a = *(const ushort4*)(p0 + i);
  const ushort4 b = *(const ushort4*)(p1 + i);
  float4 o;
  o.x = xv.x + bf2f_(a.x) + bf2f_(b.x);
  o.y = xv.y + bf2f_(a.y) + bf2f_(b.y);
  o.z = xv.z + bf2f_(a.z) + bf2f_(b.z);
  o.w = xv.w + bf2f_(a.w) + bf2f_(b.w);
  *(float4*)(out + i) = o;
}

// ============ 128x128 2-phase GEMM, BK=64, 8 waves ============
// M-major grid (XCD = m-block%8). All ops 1-term plain bf16 (r23-validated: absmax
// pinned at 0.03125 through every lo-term drop). SPLITK=1 (fc2): z in {0,1} computes
// K-chunk z*NKT*64..+NKT*64 (bf16 partials, bias on z=0).
// EPI: 0 bf16; 1 gelu+bf16; 2 f32 resid; 3 bf16 with 0.125 scale on cols<768.
template <int EPI, int NTERM, int NKT, int SPLITK>
__global__ __launch_bounds__(512, 2) void gemmT(
    const unsigned short* __restrict__ Ah, const unsigned short* __restrict__ Al,
    const unsigned short* __restrict__ Bh, const unsigned short* __restrict__ Bl,
    const float* __restrict__ bias, const float* __restrict__ resid,
    void* __restrict__ outp, int N, int K) {
  __shared__ __align__(16) char lds[65536];
  const int tid = threadIdx.x;
  const int lane = tid & 63, wid = tid >> 6;
  const int wr = wid >> 1, wc = wid & 1;  // wave -> 32-row x 64-col output region
  const int rl = lane & 15, g = lane >> 4;
  const int m0 = blockIdx.x * 128, n0 = blockIdx.y * 128;  // M-major
  const int NT = NTERM * NKT;
  const int kz = SPLITK ? (int)blockIdx.z * (NKT * 64) : 0;  // K-chunk offset

  const int srw = lane >> 3;
  const int csrc = (lane & 7) ^ srw;
  const size_t a_base = (size_t)(m0 + wid * 8 + srw) * K + csrc * 8;
  const size_t b_base = (size_t)(n0 + wid * 8 + srw) * K + csrc * 8;

  auto stageA = [&](int buf, int half, int tile) {
    const int tt = (tile < NT) ? tile : 0;
    const int term = tt / NKT, kc = tt - term * NKT;
    const unsigned short* src = (NTERM == 3 && term == 2) ? Al : Ah;
    const unsigned short* gp = src + a_base + (size_t)half * 64 * K + kc * 64 + kz;
    gload_lds16(gp, lds + buf * 16384 + half * 8192 + wid * 1024);
  };
  auto stageB = [&](int buf, int half, int tile) {
    const int tt = (tile < NT) ? tile : 0;
    const int term = tt / NKT, kc = tt - term * NKT;
    const unsigned short* src = (term == 1) ? Bl : Bh;
    const unsigned short* gp = src + b_base + (size_t)half * 64 * K + kc * 64 + kz;
    gload_lds16(gp, lds + 32768 + buf * 16384 + half * 8192 + wid * 1024);
  };
  auto rdA = [&](int buf, int mf, int s) -> bf16x8 {
    const int row = wr * 32 + mf * 16 + rl;
    const int c = (s * 4 + g) ^ (row & 7);
    return *(const bf16x8*)(lds + buf * 16384 + row * 128 + c * 16);
  };
  auto rdB = [&](int buf, int nfp, int s) -> bf16x8 {
    const int row = wc * 64 + nfp * 16 + rl;
    const int c = (s * 4 + g) ^ (row & 7);
    return *(const bf16x8*)(lds + 32768 + buf * 16384 + row * 128 + c * 16);
  };

  f32x4 acc[2][4];
#pragma unroll
  for (int i = 0; i < 2; ++i)
#pragma unroll
    for (int j = 0; j < 4; ++j) acc[i][j] = 0.0f;

  bf16x8 af[2][2], bfr[2][2];

  stageA(0, 0, 0); stageA(0, 1, 0);
  stageB(0, 0, 0); stageB(0, 1, 0);
  stageA(1, 0, 1); stageA(1, 1, 1);
  asm volatile("s_waitcnt vmcnt(2)" ::: "memory");
  __builtin_amdgcn_s_barrier();

#define TILE(P, T)                                                                \
  {                                                                               \
    _Pragma("unroll") for (int mf = 0; mf < 2; ++mf)                              \
    _Pragma("unroll") for (int s = 0; s < 2; ++s) af[mf][s] = rdA(P, mf, s);      \
    _Pragma("unroll") for (int nf = 0; nf < 2; ++nf)                              \
    _Pragma("unroll") for (int s = 0; s < 2; ++s) bfr[nf][s] = rdB(P, nf, s);     \
    stageB((P) ^ 1, 0, (T) + 1);                                                  \
    stageB((P) ^ 1, 1, (T) + 1);                                                  \
    __builtin_amdgcn_s_barrier();                                                 \
    asm volatile("s_waitcnt lgkmcnt(0)" ::: "memory");                            \
    __builtin_amdgcn_sched_barrier(0);                                            \
    __builtin_amdgcn_s_setprio(1);                                                \
    _Pragma("unroll") for (int mf = 0; mf < 2; ++mf)                              \
    _Pragma("unroll") for (int nf = 0; nf < 2; ++nf)                              \
    _Pragma("unroll") for (int s = 0; s < 2; ++s)                                 \
        acc[mf][nf] = mfma16(af[mf][s], bfr[nf][s], acc[mf][nf]);                 \
    __builtin_amdgcn_s_setprio(0);                                                \
    __builtin_amdgcn_s_barrier();                                                 \
    _Pragma("unroll") for (int nf = 0; nf < 2; ++nf)                              \
    _Pragma("unroll") for (int s = 0; s < 2; ++s) bfr[nf][s] = rdB(P, 2 + nf, s); \
    stageA(P, 0, (T) + 2);                                                        \
    stageA(P, 1, (T) + 2);                                                        \
    __builtin_amdgcn_s_barrier();                                                 \
    asm volatile("s_waitcnt lgkmcnt(0)" ::: "memory");                            \
    __builtin_amdgcn_sched_barrier(0);                                            \
    __builtin_amdgcn_s_setprio(1);                                                \
    _Pragma("unroll") for (int mf = 0; mf < 2; ++mf)                              \
    _Pragma("unroll") for (int nf = 0; nf < 2; ++nf)                              \
    _Pragma("unroll") for (int s = 0; s < 2; ++s)                                 \
        acc[mf][2 + nf] = mfma16(af[mf][s], bfr[nf][s], acc[mf][2 + nf]);         \
    __builtin_amdgcn_s_setprio(0);                                                \
    asm volatile("s_waitcnt vmcnt(2)" ::: "memory");                              \
    __builtin_amdgcn_s_barrier();                                                 \
  }

  for (int t = 0; t < NT; t += 2) {
    TILE(0, t)
    TILE(1, t + 1)
  }
#undef TILE

  __hip_bfloat16* outb16 = (__hip_bfloat16*)outp;
  if (SPLITK)
    outb16 += (size_t)blockIdx.z * (size_t)gridDim.x * 128 * (size_t)N;
  float* outf = (float*)outp;
#pragma unroll
  for (int nfp = 0; nfp < 4; ++nfp) {
    const int col = n0 + wc * 64 + nfp * 16 + rl;
    float bia = bias[col];
    if (SPLITK && blockIdx.z) bia = 0.0f;
#pragma unroll
    for (int mf = 0; mf < 2; ++mf) {
      const int rowb = m0 + wr * 32 + mf * 16 + g * 4;
#pragma unroll
      for (int r = 0; r < 4; ++r) {
        float val = acc[mf][nfp][r] + bia;
        const size_t idx = (size_t)(rowb + r) * N + col;
        if (EPI == 1) val = gelu_f(val);
        if (EPI == 3 && col < 768) val *= 0.125f;  // attention scale folded into Q
        if (EPI == 2)
          outf[idx] = resid[idx] + val;
        else
          outb16[idx] = __float2bfloat16(val);
      }
    }
  }
}

// ---------------- fused causal attention (swapped-QK^T, KVBLK=128, XCD-local grid) ----------------
// r19 checkpoint structure (best verified: 57us, VGPR 84). Q pre-scaled by 0.125.
__global__ __launch_bounds__(256) void attn_kernel(
    const unsigned short* __restrict__ qkv, unsigned short* __restrict__ yh) {
  const int T = 2048, C3 = 2304, NH = 12;
  const int bh = blockIdx.x;            // 0..23 -> XCD = bh%8
  const int bq = blockIdx.y;            // 0..31
  const int qt = (bq & 1) ? (31 - (bq >> 1)) : (bq >> 1);  // long/short pairing
  const int b = bh / NH, h = bh % NH;
  const int tid = threadIdx.x, lane = tid & 63, w = tid >> 6;
  const int rl = lane & 15, g = lane >> 4;
  __shared__ __align__(16) unsigned short Kl[128 * 64];     // [kv][d]   16KB
  __shared__ __align__(16) unsigned short Vt[64 * 128];     // [d][kv]   16KB
  __shared__ __align__(16) unsigned short Pl[4][16 * 128];  // per-wave [q][kv] 16KB
  const size_t base = (size_t)b * T * C3;
  const int hq = h * 64, hk = 768 + h * 64, hv = 1536 + h * 64;
  const int qr0 = qt * 64 + w * 16;
  const int qrow = qr0 + rl;  // this lane's q row (swapped layout)

  bf16x8 qf[2];
#pragma unroll
  for (int c = 0; c < 2; ++c)
    qf[c] = *(const bf16x8*)(qkv + base + (size_t)(qr0 + rl) * C3 + hq + 32 * c + 8 * g);

  const int kr = tid >> 1, kh = tid & 1;
  const int va = tid & 31, vdg = tid >> 5;
  const unsigned short* Kg = qkv + base + (size_t)kr * C3 + hk + kh * 32;
  const unsigned short* Vg = qkv + base + (size_t)(4 * va) * C3 + hv + vdg * 8;

  f32x4 o[4];  // o[nf][r] = O^T[d = nf*16 + g*4 + r][q = rl]
  float m_r = -1e30f, s_r = 0.0f;
#pragma unroll
  for (int i = 0; i < 4; ++i) o[i] = 0.0f;

  const int nt2 = (qt + 2) >> 1;  // ceil((qt+1)*64 / 128)
  bf16x8 kp[4], vp[4];
#pragma unroll
  for (int i = 0; i < 4; ++i) kp[i] = *(const bf16x8*)(Kg + i * 8);
#pragma unroll
  for (int i = 0; i < 4; ++i) vp[i] = *(const bf16x8*)(Vg + (size_t)i * C3);

  unsigned short* Pw = Pl[w];

  for (int t = 0; t < nt2; ++t) {
    __syncthreads();  // LDS free (prev tile's compute done)
#pragma unroll
    for (int i = 0; i < 4; ++i)
      *(bf16x8*)((char*)Kl + kr * 128 + (((kh * 4 + i) ^ (kr & 7)) << 4)) = kp[i];
#pragma unroll
    for (int i = 0; i < 8; ++i) {
      const int d = vdg * 8 + i;
      unsigned long long wv =
          (unsigned long long)(unsigned short)vp[0][i] |
          ((unsigned long long)(unsigned short)vp[1][i] << 16) |
          ((unsigned long long)(unsigned short)vp[2][i] << 32) |
          ((unsigned long long)(unsigned short)vp[3][i] << 48);
      *(unsigned long long*)((char*)Vt + d * 256 + (((va >> 1) ^ i) << 4) +
                             (va & 1) * 8) = wv;
    }
    __syncthreads();  // LDS ready
    if (t + 1 < nt2) {
      const unsigned short* nk = Kg + (size_t)(t + 1) * 128 * C3;
      const unsigned short* nv = Vg + (size_t)(t + 1) * 128 * C3;
#pragma unroll
      for (int i = 0; i < 4; ++i) kp[i] = *(const bf16x8*)(nk + i * 8);
#pragma unroll
      for (int i = 0; i < 4; ++i) vp[i] = *(const bf16x8*)(nv + (size_t)i * C3);
    }

    // ---- S^T = K Q^T (swapped): s[ch][r] = S[kv=ch*16+g*4+r][q=rl] ----
    f32x4 s[8];
#pragma unroll
    for (int ch = 0; ch < 8; ++ch) s[ch] = 0.0f;
#pragma unroll
    for (int c = 0; c < 2; ++c)
#pragma unroll
      for (int ch = 0; ch < 8; ++ch) {
        bf16x8 kb = *(const bf16x8*)((char*)Kl + (ch * 16 + rl) * 128 +
                                     ((((c << 2) | g) ^ (rl & 7)) << 4));
        s[ch] = mfma16(kb, qf[c], s[ch]);
      }

    // ---- lane-local softmax over this lane's 32 kv scores (q=rl) ----
    const bool diag = (t == nt2 - 1);
    const int kv0 = t * 128;
    float mx = -1e30f;
#pragma unroll
    for (int ch = 0; ch < 8; ++ch)
#pragma unroll
      for (int r = 0; r < 4; ++r) {
        float v = s[ch][r];  // Q pre-scaled in qkv epilogue
        if (diag) v = (kv0 + ch * 16 + g * 4 + r > qrow) ? -1e30f : v;
        s[ch][r] = v;
        mx = fmaxf(mx, v);
      }
    mx = fmaxf(mx, __shfl_xor(mx, 16));
    mx = fmaxf(mx, __shfl_xor(mx, 32));
    // defer-max (T13): rescale only when max grew past THR=8
    if (!__all(mx - m_r <= 8.0f)) {
      const float mnew = fmaxf(m_r, mx);
      const float fs = __expf(m_r - mnew);
      s_r *= fs;
#pragma unroll
      for (int nf = 0; nf < 4; ++nf)
#pragma unroll
        for (int r = 0; r < 4; ++r) o[nf][r] *= fs;
      m_r = mnew;
    }
    float rs = 0.0f;
#pragma unroll
    for (int ch = 0; ch < 8; ++ch)
#pragma unroll
      for (int r = 0; r < 4; ++r) {
        const float e = __expf(s[ch][r] - m_r);
        s[ch][r] = e;  // p stored in place
        rs += e;
      }
    rs += __shfl_xor(rs, 16);
    rs += __shfl_xor(rs, 32);
    s_r += rs;

    // ---- write P row q=rl (packed b64, swizzle key rl&7) ----
#pragma unroll
    for (int ch = 0; ch < 8; ++ch) {
      uint2 pk;
      pk.x = (unsigned int)f2bf(s[ch][0]) | ((unsigned int)f2bf(s[ch][1]) << 16);
      pk.y = (unsigned int)f2bf(s[ch][2]) | ((unsigned int)f2bf(s[ch][3]) << 16);
      *(uint2*)((char*)Pw + rl * 256 + (((2 * ch + (g >> 1)) ^ (rl & 7)) << 4) +
                (g & 1) * 8) = pk;
    }

    // ---- O^T += V^T P (swapped): same-wave ds dependency, no barrier ----
#pragma unroll
    for (int kb = 0; kb < 4; ++kb) {
      bf16x8 pa = *(const bf16x8*)((char*)Pw + rl * 256 +
                                   (((kb * 4 + g) ^ (rl & 7)) << 4));
#pragma unroll
      for (int nf = 0; nf < 4; ++nf) {
        bf16x8 vb = *(const bf16x8*)((char*)Vt + (nf * 16 + rl) * 256 +
                                     (((kb * 4 + g) ^ (rl & 7)) << 4));
        o[nf] = mfma16(vb, pa, o[nf]);
      }
    }
  }

  // ---- epilogue ----
  const float inv = 1.0f / s_r;
  const size_t rowb = (size_t)(b * T + qr0 + rl) * 768 + hq;
#pragma unroll
  for (int nf = 0; nf < 4; ++nf) {
    ushort4 oh;
    oh.x = f2bf(o[nf][0] * inv);
    oh.y = f2bf(o[nf][1] * inv);
    oh.z = f2bf(o[nf][2] * inv);
    oh.w = f2bf(o[nf][3] * inv);
    *(ushort4*)(yh + rowb + nf * 16 + g * 4) = oh;
  }
}

// ---------------- host launch ----------------
extern "C" void kernel_launch(void* const* d_in, const int* in_sizes, int n_in,
                              void* d_out, int out_size, void* d_ws, size_t ws_size,
                              hipStream_t stream) {
  const float* x    = (const float*)d_in[0];
  const float* ln1w = (const float*)d_in[1];
  const float* ln1b = (const float*)d_in[2];
  const float* qkvw = (const float*)d_in[3];
  const float* qkvb = (const float*)d_in[4];
  const float* outw = (const float*)d_in[5];
  const float* outb = (const float*)d_in[6];
  const float* fc1w = (const float*)d_in[7];
  const float* fc1b = (const float*)d_in[8];
  const float* fc2w = (const float*)d_in[9];
  const float* fc2b = (const float*)d_in[10];
  float* outp = (float*)d_out;

  char* ws = (char*)d_ws;
  unsigned short* qkvw_h = (unsigned short*)ws;  ws += (size_t)2304 * 768 * 2;
  unsigned short* outw_h = (unsigned short*)ws;  ws += (size_t)768 * 768 * 2;
  unsigned short* fc1w_h = (unsigned short*)ws;  ws += (size_t)3072 * 768 * 2;
  unsigned short* fc2w_h = (unsigned short*)ws;  ws += (size_t)768 * 3072 * 2;
  unsigned short* h_h    = (unsigned short*)ws;  ws += (size_t)4096 * 768 * 2;
  unsigned short* y_h    = (unsigned short*)ws;  ws += (size_t)4096 * 768 * 2;
  float*          x1     = (float*)ws;           ws += (size_t)4096 * 768 * 4;
  unsigned short* big    = (unsigned short*)ws;  // qkv (18.9MB) then fc1-out g (25.2MB)
  unsigned short* qkv_bf = big;
  unsigned short* g_bf   = big;
  // fc2 split-K partials (bf16, 2 x 4096x768) reuse h_h..y_h (dead after fc1)
  unsigned short* part   = h_h;

  // all 4 weight transposes (hi only) in one launch
  transpose_all<<<6912, 256, 0, stream>>>(qkvw, outw, fc1w, fc2w,
                                          qkvw_h, outw_h, fc1w_h, fc2w_h);

  // h = LN(x) -> bf16 hi
  ln_hi<<<4096, 192, 0, stream>>>(x, ln1w, ln1b, h_h);
  // qkv = h @ qkv_w + qkv_b  (bf16 out, Q pre-scaled by 0.125) — M-major
  gemmT<3, 1, 12, 0><<<dim3(32, 18), 512, 0, stream>>>(h_h, nullptr, qkvw_h, nullptr,
                                                       qkvb, nullptr, qkv_bf, 2304, 768);
  // y = attention(qkv), bf16 out — grid (bh, q) for XCD L2 locality
  attn_kernel<<<dim3(24, 32), 256, 0, stream>>>(qkv_bf, y_h);
  // x1 = x + y @ out_w + out_b  (f32 resid out) — M-major
  gemmT<2, 1, 12, 0><<<dim3(32, 6), 512, 0, stream>>>(y_h, nullptr, outw_h, nullptr,
                                                      outb, x, x1, 768, 768);
  // h = LN(x1) -> bf16 hi
  ln_hi<<<4096, 192, 0, stream>>>(x1, ln1w, ln1b, h_h);
  // g = gelu(h @ fc1_w + fc1_b)  (fast-gelu bf16 out) — M-major
  gemmT<1, 1, 12, 0><<<dim3(32, 24), 512, 0, stream>>>(h_h, nullptr, fc1w_h, nullptr,
                                                       fc1b, nullptr, g_bf, 3072, 768);
  // fc2: split-K over K-halves (z=0: K 0..1535 +bias; z=1: K 1536..3071)
  gemmT<0, 1, 24, 1><<<dim3(32, 6, 2), 512, 0, stream>>>(g_bf, nullptr, fc2w_h, nullptr,
                                                         fc2b, nullptr, part, 768, 3072);
  // out = x1 + p0 + p1
  fc2_reduce<<<3072, 256, 0, stream>>>(x1, part, part + (size_t)4096 * 768, outp);
}